// Round 2
// baseline (420.299 us; speedup 1.0000x reference)
//
#include <hip/hip_runtime.h>
#include <math.h>

#define PI_F 3.14159265358979323846f
#define XQS 580   // quad-row stride (floats): [c/4][col*4+(c&3)], 144 cols padded to 145 quads

// 64->16 conv layer (l4/l5): wave-uniform 8-output block, lanes <-> columns.
__device__ __forceinline__ void conv64_16(
    const float* __restrict__ Wl, const float* __restrict__ blv,
    const float* __restrict__ Wg, const float* __restrict__ bgv,
    const float* __restrict__ xin, float* __restrict__ xout,
    int lane, int wid)
{
    int ob = __builtin_amdgcn_readfirstlane(wid);   // 0..7
    int rb = (ob & 3) * 8;
    const float* W  = (ob < 4) ? Wl  : Wg;
    const float* bv = (ob < 4) ? blv : bgv;
    int crow = (ob < 4) ? rb : 32 + rb;             // output c-row in xq layout
    int q0 = crow >> 2;

    int colA = lane, colB = lane + 64;
    float accA[8], accB[8];
    #pragma unroll
    for (int oi = 0; oi < 8; ++oi) { float bb = bv[rb+oi]; accA[oi] = bb; accB[oi] = bb; }
    #pragma unroll 4
    for (int c4 = 0; c4 < 16; ++c4) {
        float4 xA = *(const float4*)&xin[c4*XQS + colA*4];
        float4 xB = *(const float4*)&xin[c4*XQS + colB*4];
        #pragma unroll
        for (int oi = 0; oi < 8; ++oi) {
            float4 w = *(const float4*)&W[(rb+oi)*64 + c4*4];
            accA[oi] = fmaf(w.x, xA.x, accA[oi]); accA[oi] = fmaf(w.y, xA.y, accA[oi]);
            accA[oi] = fmaf(w.z, xA.z, accA[oi]); accA[oi] = fmaf(w.w, xA.w, accA[oi]);
            accB[oi] = fmaf(w.x, xB.x, accB[oi]); accB[oi] = fmaf(w.y, xB.y, accB[oi]);
            accB[oi] = fmaf(w.z, xB.z, accB[oi]); accB[oi] = fmaf(w.w, xB.w, accB[oi]);
        }
    }
    *(float4*)&xout[ q0   *XQS + colA*4] = make_float4(fmaxf(accA[0],0.f),fmaxf(accA[1],0.f),fmaxf(accA[2],0.f),fmaxf(accA[3],0.f));
    *(float4*)&xout[(q0+1)*XQS + colA*4] = make_float4(fmaxf(accA[4],0.f),fmaxf(accA[5],0.f),fmaxf(accA[6],0.f),fmaxf(accA[7],0.f));
    *(float4*)&xout[ q0   *XQS + colB*4] = make_float4(fmaxf(accB[0],0.f),fmaxf(accB[1],0.f),fmaxf(accB[2],0.f),fmaxf(accB[3],0.f));
    *(float4*)&xout[(q0+1)*XQS + colB*4] = make_float4(fmaxf(accB[4],0.f),fmaxf(accB[5],0.f),fmaxf(accB[6],0.f),fmaxf(accB[7],0.f));

    // tail: cols 128..143 (valid work on lanes<16; others compute a dup col, stores guarded)
    int colC = 128 + (lane & 15);
    float accC[8];
    #pragma unroll
    for (int oi = 0; oi < 8; ++oi) accC[oi] = bv[rb+oi];
    #pragma unroll 4
    for (int c4 = 0; c4 < 16; ++c4) {
        float4 xC = *(const float4*)&xin[c4*XQS + colC*4];
        #pragma unroll
        for (int oi = 0; oi < 8; ++oi) {
            float4 w = *(const float4*)&W[(rb+oi)*64 + c4*4];
            accC[oi] = fmaf(w.x, xC.x, accC[oi]); accC[oi] = fmaf(w.y, xC.y, accC[oi]);
            accC[oi] = fmaf(w.z, xC.z, accC[oi]); accC[oi] = fmaf(w.w, xC.w, accC[oi]);
        }
    }
    if (lane < 16) {
        *(float4*)&xout[ q0   *XQS + colC*4] = make_float4(fmaxf(accC[0],0.f),fmaxf(accC[1],0.f),fmaxf(accC[2],0.f),fmaxf(accC[3],0.f));
        *(float4*)&xout[(q0+1)*XQS + colC*4] = make_float4(fmaxf(accC[4],0.f),fmaxf(accC[5],0.f),fmaxf(accC[6],0.f),fmaxf(accC[7],0.f));
    }
}

// reduce raw global-path relus (rows 32..63 of xout) to means, broadcast-fill them back
__device__ __forceinline__ void gmean_fill(float* __restrict__ xout, float* __restrict__ gmp,
                                           float* __restrict__ xms, int tid)
{
    __syncthreads();
    if (tid < 128) {
        int j = tid >> 2, q = tid & 3;
        int cc = 32 + j; int qr = cc >> 2, cb = cc & 3;
        float s = 0.f;
        for (int col = q*36; col < q*36+36; ++col) s += xout[qr*XQS + col*4 + cb];
        gmp[tid] = s;
    }
    __syncthreads();
    if (tid < 32) xms[tid] = (gmp[tid*4]+gmp[tid*4+1]+gmp[tid*4+2]+gmp[tid*4+3]) * (1.f/144.f);
    __syncthreads();
    for (int t = tid; t < 4608; t += 512) {
        int col = t >> 5, j = t & 31;
        int cc = 32 + j;
        xout[(cc>>2)*XQS + col*4 + (cc&3)] = xms[j];
    }
    __syncthreads();
}

__global__ __launch_bounds__(512) void kfull(
    const float* __restrict__ ch,
    const float* __restrict__ wl1, const float* __restrict__ bl1,
    const float* __restrict__ wg1, const float* __restrict__ bg1,
    const float* __restrict__ wl2, const float* __restrict__ bl2,
    const float* __restrict__ wg2, const float* __restrict__ bg2,
    const float* __restrict__ wl3, const float* __restrict__ bl3,
    const float* __restrict__ wg3, const float* __restrict__ bg3,
    const float* __restrict__ wl4, const float* __restrict__ bl4,
    const float* __restrict__ wg4, const float* __restrict__ bg4,
    const float* __restrict__ wl5, const float* __restrict__ bl5,
    const float* __restrict__ wg5, const float* __restrict__ bg5,
    const float* __restrict__ wl6, const float* __restrict__ bl6,
    const float* __restrict__ wg6, const float* __restrict__ bg6,
    const float* __restrict__ wl7, const float* __restrict__ bl7,
    const float* __restrict__ wg7, const float* __restrict__ bg7,
    const float* __restrict__ wl8, const float* __restrict__ bl8,
    const int* __restrict__ perm3, const int* __restrict__ perm6,
    float* __restrict__ out)
{
    __shared__ float xAT[16*XQS];     // x4 (and l1/l2 scratch)
    __shared__ float xBT[16*XQS];     // x3 then x5
    __shared__ float f2l[1024];
    __shared__ float cat3T[16*226];
    __shared__ float g3m[231];
    __shared__ float gmp[128];
    __shared__ float xms[32];
    __shared__ float xls[160];
    __shared__ int   pfn3[144];
    __shared__ int   pml[1296];
    __shared__ int   cnt[1008];
    __shared__ float l8v[1008];
    __shared__ float g6m[224];
    __shared__ float sgf[448];
    __shared__ float redbuf[8];
    __shared__ float CbS;

    const int tid = threadIdx.x;
    const int lane = tid & 63, wid = tid >> 6;
    const int b = blockIdx.x;
    float* f1s = xAT;           // 64*16
    float* gts = xAT + 1024;    // 32*16

    // ---- P0: init
    for (int t = tid; t < 1008; t += 512) cnt[t] = 0;
    if (tid < 224) g6m[tid] = 0.f;
    if (tid < 160) xls[tid] = ch[b*160 + tid];
    if (tid < 144) pfn3[tid] = perm3[tid];
    __syncthreads();

    // ---- P1: perm6 decode + counts; layer 1
    for (int t = tid; t < 1296; t += 512) { int p = perm6[t]; pml[t] = p; atomicAdd(&cnt[p], 1); }
    #pragma unroll
    for (int it = 0; it < 2; ++it) {
        int t = tid + it*512; int o = t >> 4, n = t & 15;
        int isg = o >= 32, oo = o & 31;
        const float* w = isg ? wg1 : wl1;
        float acc = (isg ? bg1 : bl1)[oo];
        #pragma unroll
        for (int c = 0; c < 10; ++c) acc = fmaf(w[oo*10+c], xls[c*16+n], acc);
        acc = fmaxf(acc, 0.f);
        if (isg) gts[oo*16+n] = acc; else f1s[o*16+n] = acc;
    }
    __syncthreads();
    if (tid < 32) {
        float s = 0.f;
        #pragma unroll
        for (int n = 0; n < 16; ++n) s += gts[tid*16+n];
        s *= (1.f/16.f);
        #pragma unroll
        for (int n = 0; n < 16; ++n) f1s[(32+tid)*16+n] = s;
    }
    __syncthreads();

    // ---- layer 2
    #pragma unroll
    for (int it = 0; it < 2; ++it) {
        int t = tid + it*512; int o = t >> 4, n = t & 15;
        int isg = o >= 32, oo = o & 31;
        const float* w = isg ? wg2 : wl2;
        float acc = (isg ? bg2 : bl2)[oo];
        #pragma unroll
        for (int c = 0; c < 64; ++c) acc = fmaf(w[oo*64+c], f1s[c*16+n], acc);
        acc = fmaxf(acc, 0.f);
        if (isg) gts[oo*16+n] = acc; else f2l[o*16+n] = acc;
    }
    __syncthreads();
    if (tid < 32) {
        float s = 0.f;
        #pragma unroll
        for (int n = 0; n < 16; ++n) s += gts[tid*16+n];
        s *= (1.f/16.f);
        #pragma unroll
        for (int n = 0; n < 16; ++n) f2l[(32+tid)*16+n] = s;
    }
    __syncthreads();

    // ---- layer 3: wave-row scheme. 448 rows (0..223 local, 224..447 global)
    {
        int n16 = lane & 15, cs = lane >> 4;
        float xr[16];
        #pragma unroll
        for (int i = 0; i < 16; ++i) xr[i] = f2l[cs*256 + i*16 + n16];
        int wq = __builtin_amdgcn_readfirstlane(wid);
        int isg = wq >= 4;
        #pragma unroll 2
        for (int k = 0; k < 56; ++k) {
            int r = wq*56 + k;
            int rr = isg ? r - 224 : r;
            const float* wrow = (isg ? wg3 : wl3) + rr*64 + cs*16;
            float s0 = 0.f, s1 = 0.f;
            #pragma unroll
            for (int q = 0; q < 4; ++q) {
                float4 w = ((const float4*)wrow)[q];
                if (q & 1) {
                    s1 = fmaf(w.x, xr[q*4+0], s1); s1 = fmaf(w.y, xr[q*4+1], s1);
                    s1 = fmaf(w.z, xr[q*4+2], s1); s1 = fmaf(w.w, xr[q*4+3], s1);
                } else {
                    s0 = fmaf(w.x, xr[q*4+0], s0); s0 = fmaf(w.y, xr[q*4+1], s0);
                    s0 = fmaf(w.z, xr[q*4+2], s0); s0 = fmaf(w.w, xr[q*4+3], s0);
                }
            }
            float s = s0 + s1;
            s += __shfl_xor(s, 16);
            s += __shfl_xor(s, 32);
            s = fmaxf(s + (isg ? bg3 : bl3)[rr], 0.f);
            if (!isg) {
                if (cs == 0) cat3T[n16*226 + rr] = s;
            } else {
                s += __shfl_xor(s, 1); s += __shfl_xor(s, 2);
                s += __shfl_xor(s, 4); s += __shfl_xor(s, 8);
                if (lane == 0) g3m[(rr >> 5)*33 + (rr & 31)] = s * (1.f/16.f);
            }
        }
    }
    __syncthreads();

    // ---- gather into x3 (xBT, quad layout): col w, c<32 local / c>=32 g3m
    for (int t = tid; t < 9216; t += 512) {
        int c4 = t / 576, rem = t - c4*576;
        int col = rem >> 2, ci = rem & 3;
        int c = c4*4 + ci;
        int p3 = pfn3[col]; int pf = p3 >> 4, pn = p3 & 15;
        float v = (c < 32) ? cat3T[pn*226 + pf*32 + c] : g3m[pf*33 + (c - 32)];
        xBT[c4*XQS + col*4 + ci] = v;
    }
    __syncthreads();

    // ---- layer 4, layer 5
    conv64_16(wl4, bl4, wg4, bg4, xBT, xAT, lane, wid);
    gmean_fill(xAT, gmp, xms, tid);
    conv64_16(wl5, bl5, wg5, bg5, xAT, xBT, lane, wid);
    gmean_fill(xBT, gmp, xms, tid);   // xms = x5 global means; xBT fully = x5

    // ---- g6 means (f<7): mean over 144 cols of relu(wg6[f] . x5col)
    #pragma unroll
    for (int it = 0; it < 2; ++it) {
        int t = tid + it*512;
        if (t < 896) {
            int f = t >> 7, j = (t >> 2) & 31, q = t & 3;
            const float* wr = wg6 + (f*32+j)*64;
            float wreg[64];
            #pragma unroll
            for (int k4 = 0; k4 < 16; ++k4) {
                float4 wv = ((const float4*)wr)[k4];
                wreg[k4*4] = wv.x; wreg[k4*4+1] = wv.y; wreg[k4*4+2] = wv.z; wreg[k4*4+3] = wv.w;
            }
            float bb = bg6[f*32+j];
            #pragma unroll
            for (int i = 0; i < 32; ++i) bb = fmaf(wreg[32+i], xms[i], bb);
            float s = 0.f;
            for (int n = q*36; n < q*36+36; ++n) {
                float acc = bb;
                #pragma unroll
                for (int c4 = 0; c4 < 8; ++c4) {
                    float4 xv = *(const float4*)&xBT[c4*XQS + n*4];
                    acc = fmaf(wreg[c4*4],   xv.x, acc);
                    acc = fmaf(wreg[c4*4+1], xv.y, acc);
                    acc = fmaf(wreg[c4*4+2], xv.z, acc);
                    acc = fmaf(wreg[c4*4+3], xv.w, acc);
                }
                s += fmaxf(acc, 0.f);
            }
            atomicAdd(&g6m[f*32+j], s);
        }
    }
    __syncthreads();
    if (tid < 224) g6m[tid] *= (1.f/144.f);
    __syncthreads();

    // ---- sgf[f][o7]: bias + W7_global-part . g6m[f]  (column-independent)
    if (tid < 448) {
        int f = wid;           // waves 0..6, uniform
        int o7 = lane;
        const float* wr; float bb;
        if (o7 < 32) { wr = wl7 + o7*64; bb = bl7[o7]; }
        else         { wr = wg7 + (o7-32)*64; bb = bg7[o7-32]; }
        float s = bb;
        #pragma unroll
        for (int i4 = 0; i4 < 8; ++i4) {
            float4 w = ((const float4*)(wr + 32))[i4];
            s = fmaf(w.x, g6m[f*32 + i4*4+0], s);
            s = fmaf(w.y, g6m[f*32 + i4*4+1], s);
            s = fmaf(w.z, g6m[f*32 + i4*4+2], s);
            s = fmaf(w.w, g6m[f*32 + i4*4+3], s);
        }
        sgf[f*64 + o7] = s;
    }
    __syncthreads();

    // ---- main: per-column l6 -> l7 -> l8 scalars. waves 0..6 <-> filter f.
    float gacc = 0.f;
    if (wid < 7) {
        int f = __builtin_amdgcn_readfirstlane(wid);
        const float* W6f = wl6 + f*2048;
        const float* sgff = sgf + f*64;
        int colA = lane, colB = lane + 64;
        float accA[32], accB[32];
        #pragma unroll
        for (int o = 0; o < 32; ++o) { float bb = bl6[f*32+o]; accA[o] = bb; accB[o] = bb; }
        #pragma unroll 2
        for (int c4 = 0; c4 < 16; ++c4) {
            float4 xA = *(const float4*)&xBT[c4*XQS + colA*4];
            float4 xB = *(const float4*)&xBT[c4*XQS + colB*4];
            #pragma unroll
            for (int o = 0; o < 32; ++o) {
                float4 w = *(const float4*)&W6f[o*64 + c4*4];
                accA[o] = fmaf(w.x, xA.x, accA[o]); accA[o] = fmaf(w.y, xA.y, accA[o]);
                accA[o] = fmaf(w.z, xA.z, accA[o]); accA[o] = fmaf(w.w, xA.w, accA[o]);
                accB[o] = fmaf(w.x, xB.x, accB[o]); accB[o] = fmaf(w.y, xB.y, accB[o]);
                accB[o] = fmaf(w.z, xB.z, accB[o]); accB[o] = fmaf(w.w, xB.w, accB[o]);
            }
        }
        #pragma unroll
        for (int o = 0; o < 32; ++o) { accA[o] = fmaxf(accA[o], 0.f); accB[o] = fmaxf(accB[o], 0.f); }
        float cAf = (float)cnt[f*144 + colA], cBf = (float)cnt[f*144 + colB];
        float l8aA = 0.f, l8aB = 0.f;
        #pragma unroll 2
        for (int o7 = 0; o7 < 32; ++o7) {                 // l7 local rows
            const float* wr = wl7 + o7*64;
            float pA[4] = {0,0,0,0}, pB[4] = {0,0,0,0};
            #pragma unroll
            for (int q = 0; q < 8; ++q) {
                float4 w = ((const float4*)wr)[q];
                pA[q&3] = fmaf(w.x, accA[q*4+0], pA[q&3]); pA[q&3] = fmaf(w.y, accA[q*4+1], pA[q&3]);
                pA[q&3] = fmaf(w.z, accA[q*4+2], pA[q&3]); pA[q&3] = fmaf(w.w, accA[q*4+3], pA[q&3]);
                pB[q&3] = fmaf(w.x, accB[q*4+0], pB[q&3]); pB[q&3] = fmaf(w.y, accB[q*4+1], pB[q&3]);
                pB[q&3] = fmaf(w.z, accB[q*4+2], pB[q&3]); pB[q&3] = fmaf(w.w, accB[q*4+3], pB[q&3]);
            }
            float base = sgff[o7];
            float vA = fmaxf(base + ((pA[0]+pA[1])+(pA[2]+pA[3])), 0.f);
            float vB = fmaxf(base + ((pB[0]+pB[1])+(pB[2]+pB[3])), 0.f);
            float wgt = wl8[o7];
            l8aA = fmaf(wgt, vA, l8aA); l8aB = fmaf(wgt, vB, l8aB);
        }
        #pragma unroll 2
        for (int o7 = 0; o7 < 32; ++o7) {                 // l7 global rows
            const float* wr = wg7 + o7*64;
            float pA[4] = {0,0,0,0}, pB[4] = {0,0,0,0};
            #pragma unroll
            for (int q = 0; q < 8; ++q) {
                float4 w = ((const float4*)wr)[q];
                pA[q&3] = fmaf(w.x, accA[q*4+0], pA[q&3]); pA[q&3] = fmaf(w.y, accA[q*4+1], pA[q&3]);
                pA[q&3] = fmaf(w.z, accA[q*4+2], pA[q&3]); pA[q&3] = fmaf(w.w, accA[q*4+3], pA[q&3]);
                pB[q&3] = fmaf(w.x, accB[q*4+0], pB[q&3]); pB[q&3] = fmaf(w.y, accB[q*4+1], pB[q&3]);
                pB[q&3] = fmaf(w.z, accB[q*4+2], pB[q&3]); pB[q&3] = fmaf(w.w, accB[q*4+3], pB[q&3]);
            }
            float base = sgff[32+o7];
            float vA = fmaxf(base + ((pA[0]+pA[1])+(pA[2]+pA[3])), 0.f);
            float vB = fmaxf(base + ((pB[0]+pB[1])+(pB[2]+pB[3])), 0.f);
            float wgt = wl8[32+o7];
            gacc = fmaf(wgt, fmaf(cAf, vA, cBf*vB), gacc);
        }
        l8v[f*144 + colA] = l8aA;
        l8v[f*144 + colB] = l8aB;

        // tail col (valid on lanes<16)
        int colC = 128 + (lane & 15);
        float accC[32];
        #pragma unroll
        for (int o = 0; o < 32; ++o) accC[o] = bl6[f*32+o];
        #pragma unroll 2
        for (int c4 = 0; c4 < 16; ++c4) {
            float4 xC = *(const float4*)&xBT[c4*XQS + colC*4];
            #pragma unroll
            for (int o = 0; o < 32; ++o) {
                float4 w = *(const float4*)&W6f[o*64 + c4*4];
                accC[o] = fmaf(w.x, xC.x, accC[o]); accC[o] = fmaf(w.y, xC.y, accC[o]);
                accC[o] = fmaf(w.z, xC.z, accC[o]); accC[o] = fmaf(w.w, xC.w, accC[o]);
            }
        }
        #pragma unroll
        for (int o = 0; o < 32; ++o) accC[o] = fmaxf(accC[o], 0.f);
        float cCf = (float)cnt[f*144 + colC];
        float l8aC = 0.f, gC = 0.f;
        #pragma unroll 2
        for (int o7 = 0; o7 < 32; ++o7) {
            const float* wr = wl7 + o7*64;
            float pC[4] = {0,0,0,0};
            #pragma unroll
            for (int q = 0; q < 8; ++q) {
                float4 w = ((const float4*)wr)[q];
                pC[q&3] = fmaf(w.x, accC[q*4+0], pC[q&3]); pC[q&3] = fmaf(w.y, accC[q*4+1], pC[q&3]);
                pC[q&3] = fmaf(w.z, accC[q*4+2], pC[q&3]); pC[q&3] = fmaf(w.w, accC[q*4+3], pC[q&3]);
            }
            float vC = fmaxf(sgff[o7] + ((pC[0]+pC[1])+(pC[2]+pC[3])), 0.f);
            l8aC = fmaf(wl8[o7], vC, l8aC);
        }
        #pragma unroll 2
        for (int o7 = 0; o7 < 32; ++o7) {
            const float* wr = wg7 + o7*64;
            float pC[4] = {0,0,0,0};
            #pragma unroll
            for (int q = 0; q < 8; ++q) {
                float4 w = ((const float4*)wr)[q];
                pC[q&3] = fmaf(w.x, accC[q*4+0], pC[q&3]); pC[q&3] = fmaf(w.y, accC[q*4+1], pC[q&3]);
                pC[q&3] = fmaf(w.z, accC[q*4+2], pC[q&3]); pC[q&3] = fmaf(w.w, accC[q*4+3], pC[q&3]);
            }
            float vC = fmaxf(sgff[32+o7] + ((pC[0]+pC[1])+(pC[2]+pC[3])), 0.f);
            gC = fmaf(wl8[32+o7], cCf*vC, gC);
        }
        if (lane < 16) { l8v[f*144 + colC] = l8aC; gacc += gC; }
    }

    // ---- block-reduce gacc -> Cb
    #pragma unroll
    for (int off = 32; off > 0; off >>= 1) gacc += __shfl_down(gacc, off);
    if (lane == 0) redbuf[wid] = gacc;
    __syncthreads();
    if (tid == 0) {
        float s = 0.f;
        #pragma unroll
        for (int i = 0; i < 8; ++i) s += redbuf[i];
        CbS = bl8[0] + s * (1.f/1296.f);
    }
    __syncthreads();
    float Cb = CbS;
    for (int t = tid; t < 1296; t += 512)
        out[b*1296 + t] = PI_F * (l8v[pml[t]] + Cb);
}

extern "C" void kernel_launch(void* const* d_in, const int* in_sizes, int n_in,
                              void* d_out, int out_size, void* d_ws, size_t ws_size,
                              hipStream_t stream) {
    (void)in_sizes; (void)n_in; (void)out_size; (void)d_ws; (void)ws_size;
    const float* ch  = (const float*)d_in[0];
    const float* wl1 = (const float*)d_in[1];  const float* bl1v = (const float*)d_in[2];
    const float* wg1 = (const float*)d_in[3];  const float* bg1v = (const float*)d_in[4];
    const float* wl2 = (const float*)d_in[5];  const float* bl2v = (const float*)d_in[6];
    const float* wg2 = (const float*)d_in[7];  const float* bg2v = (const float*)d_in[8];
    const float* wl4 = (const float*)d_in[9];  const float* bl4v = (const float*)d_in[10];
    const float* wg4 = (const float*)d_in[11]; const float* bg4v = (const float*)d_in[12];
    const float* wl5 = (const float*)d_in[13]; const float* bl5v = (const float*)d_in[14];
    const float* wg5 = (const float*)d_in[15]; const float* bg5v = (const float*)d_in[16];
    const float* wl7 = (const float*)d_in[17]; const float* bl7v = (const float*)d_in[18];
    const float* wg7 = (const float*)d_in[19]; const float* bg7v = (const float*)d_in[20];
    const float* wl3 = (const float*)d_in[21]; const float* bl3v = (const float*)d_in[22];
    const float* wg3 = (const float*)d_in[23]; const float* bg3v = (const float*)d_in[24];
    const float* wl6 = (const float*)d_in[25]; const float* bl6v = (const float*)d_in[26];
    const float* wg6 = (const float*)d_in[27]; const float* bg6v = (const float*)d_in[28];
    const float* wl8 = (const float*)d_in[29]; const float* bl8v = (const float*)d_in[30];
    const int* perm3 = (const int*)d_in[31];
    const int* perm6 = (const int*)d_in[32];
    float* out = (float*)d_out;

    kfull<<<512, 512, 0, stream>>>(ch,
        wl1, bl1v, wg1, bg1v, wl2, bl2v, wg2, bg2v,
        wl3, bl3v, wg3, bg3v, wl4, bl4v, wg4, bg4v,
        wl5, bl5v, wg5, bg5v, wl6, bl6v, wg6, bg6v,
        wl7, bl7v, wg7, bg7v, wl8, bl8v, perm3, perm6, out);
}

// Round 6
// 347.670 us; speedup vs baseline: 1.2089x; 1.2089x over previous
//
#include <hip/hip_runtime.h>
#include <math.h>

#define PI_F 3.14159265358979323846f
#define XQS 580   // quad-row stride: x[c/4][col*4+(c&3)], 144 cols -> 145 quads padded

// 64->16ch conv (l4/l5): wave-uniform 8-output block, weights broadcast from LDS.
__device__ __forceinline__ void conv64_16_lds(
    const float* __restrict__ Ws,              // LDS: [0..2048) local W, [2048..4096) global W
    const float* __restrict__ blv, const float* __restrict__ bgv,
    const float* __restrict__ xin, float* __restrict__ xout,
    int lane, int ob)
{
    int rb = (ob & 3) * 8;
    const float* W  = Ws + ((ob < 4) ? 0 : 2048);
    const float* bv = (ob < 4) ? blv : bgv;
    int crow = (ob < 4) ? rb : 32 + rb;
    int q0 = crow >> 2;

    int colA = lane, colB = lane + 64;
    float accA[8], accB[8];
    #pragma unroll
    for (int oi = 0; oi < 8; ++oi) { float bb = bv[rb+oi]; accA[oi] = bb; accB[oi] = bb; }
    #pragma unroll 4
    for (int c4 = 0; c4 < 16; ++c4) {
        float4 xA = *(const float4*)&xin[c4*XQS + colA*4];
        float4 xB = *(const float4*)&xin[c4*XQS + colB*4];
        #pragma unroll
        for (int oi = 0; oi < 8; ++oi) {
            float4 w = *(const float4*)&W[(rb+oi)*64 + c4*4];
            accA[oi] = fmaf(w.x, xA.x, accA[oi]); accA[oi] = fmaf(w.y, xA.y, accA[oi]);
            accA[oi] = fmaf(w.z, xA.z, accA[oi]); accA[oi] = fmaf(w.w, xA.w, accA[oi]);
            accB[oi] = fmaf(w.x, xB.x, accB[oi]); accB[oi] = fmaf(w.y, xB.y, accB[oi]);
            accB[oi] = fmaf(w.z, xB.z, accB[oi]); accB[oi] = fmaf(w.w, xB.w, accB[oi]);
        }
    }
    *(float4*)&xout[ q0   *XQS + colA*4] = make_float4(fmaxf(accA[0],0.f),fmaxf(accA[1],0.f),fmaxf(accA[2],0.f),fmaxf(accA[3],0.f));
    *(float4*)&xout[(q0+1)*XQS + colA*4] = make_float4(fmaxf(accA[4],0.f),fmaxf(accA[5],0.f),fmaxf(accA[6],0.f),fmaxf(accA[7],0.f));
    *(float4*)&xout[ q0   *XQS + colB*4] = make_float4(fmaxf(accB[0],0.f),fmaxf(accB[1],0.f),fmaxf(accB[2],0.f),fmaxf(accB[3],0.f));
    *(float4*)&xout[(q0+1)*XQS + colB*4] = make_float4(fmaxf(accB[4],0.f),fmaxf(accB[5],0.f),fmaxf(accB[6],0.f),fmaxf(accB[7],0.f));

    int colC = 128 + (lane & 15);
    float accC[8];
    #pragma unroll
    for (int oi = 0; oi < 8; ++oi) accC[oi] = bv[rb+oi];
    #pragma unroll 4
    for (int c4 = 0; c4 < 16; ++c4) {
        float4 xC = *(const float4*)&xin[c4*XQS + colC*4];
        #pragma unroll
        for (int oi = 0; oi < 8; ++oi) {
            float4 w = *(const float4*)&W[(rb+oi)*64 + c4*4];
            accC[oi] = fmaf(w.x, xC.x, accC[oi]); accC[oi] = fmaf(w.y, xC.y, accC[oi]);
            accC[oi] = fmaf(w.z, xC.z, accC[oi]); accC[oi] = fmaf(w.w, xC.w, accC[oi]);
        }
    }
    if (lane < 16) {
        *(float4*)&xout[ q0   *XQS + colC*4] = make_float4(fmaxf(accC[0],0.f),fmaxf(accC[1],0.f),fmaxf(accC[2],0.f),fmaxf(accC[3],0.f));
        *(float4*)&xout[(q0+1)*XQS + colC*4] = make_float4(fmaxf(accC[4],0.f),fmaxf(accC[5],0.f),fmaxf(accC[6],0.f),fmaxf(accC[7],0.f));
    }
}

__device__ __forceinline__ void gmean_fill(float* __restrict__ xout, float* __restrict__ gmp,
                                           float* __restrict__ xms, int tid)
{
    __syncthreads();
    if (tid < 128) {
        int j = tid >> 2, q = tid & 3;
        int cc = 32 + j; int qr = cc >> 2, cb = cc & 3;
        float s = 0.f;
        for (int col = q*36; col < q*36+36; ++col) s += xout[qr*XQS + col*4 + cb];
        gmp[tid] = s;
    }
    __syncthreads();
    if (tid < 32) xms[tid] = (gmp[tid*4]+gmp[tid*4+1]+gmp[tid*4+2]+gmp[tid*4+3]) * (1.f/144.f);
    __syncthreads();
    for (int t = tid; t < 4608; t += 512) {
        int col = t >> 5, j = t & 31;
        int cc = 32 + j;
        xout[(cc>>2)*XQS + col*4 + (cc&3)] = xms[j];
    }
    __syncthreads();
}

// one column through l6 -> l7 -> l8 scalars. f may be uniform (waves 0-6) or per-lane (wave 7).
__device__ __forceinline__ void task_col(
    int f, int col, bool valid,
    const float* __restrict__ W6s, const float* __restrict__ W7s,
    const float* __restrict__ sgf, const float* __restrict__ bl6s,
    const float* __restrict__ wl8s, const int* __restrict__ cnt,
    const float* __restrict__ xBT, float* __restrict__ l8v, float& gacc)
{
    float4 xq[16];
    const float* xr = xBT + col*4;
    #pragma unroll
    for (int c4 = 0; c4 < 16; ++c4) xq[c4] = *(const float4*)(xr + c4*XQS);

    float acc[32];
    const float* wf = W6s + f*2048;
    const float* bf = bl6s + f*32;
    #pragma unroll
    for (int o = 0; o < 32; ++o) {
        float s = bf[o];
        const float* w0 = wf + o*64;
        #pragma unroll
        for (int c4 = 0; c4 < 16; ++c4) {
            float4 w = *(const float4*)(w0 + c4*4);
            s = fmaf(w.x, xq[c4].x, s); s = fmaf(w.y, xq[c4].y, s);
            s = fmaf(w.z, xq[c4].z, s); s = fmaf(w.w, xq[c4].w, s);
        }
        acc[o] = fmaxf(s, 0.f);
    }

    const float* sgff = sgf + f*64;
    float l8a = 0.f, gcol = 0.f;
    #pragma unroll 1
    for (int o7 = 0; o7 < 32; ++o7) {              // l7 local rows
        float s = sgff[o7];
        const float* wr = W7s + o7*32;
        #pragma unroll
        for (int q = 0; q < 8; ++q) {
            float4 w = *(const float4*)(wr + q*4);
            s = fmaf(w.x, acc[q*4+0], s); s = fmaf(w.y, acc[q*4+1], s);
            s = fmaf(w.z, acc[q*4+2], s); s = fmaf(w.w, acc[q*4+3], s);
        }
        l8a = fmaf(wl8s[o7], fmaxf(s, 0.f), l8a);
    }
    #pragma unroll 1
    for (int o7 = 0; o7 < 32; ++o7) {              // l7 global rows
        float s = sgff[32+o7];
        const float* wr = W7s + (32+o7)*32;
        #pragma unroll
        for (int q = 0; q < 8; ++q) {
            float4 w = *(const float4*)(wr + q*4);
            s = fmaf(w.x, acc[q*4+0], s); s = fmaf(w.y, acc[q*4+1], s);
            s = fmaf(w.z, acc[q*4+2], s); s = fmaf(w.w, acc[q*4+3], s);
        }
        gcol = fmaf(wl8s[32+o7], fmaxf(s, 0.f), gcol);
    }
    if (valid) l8v[f*144+col] = l8a;
    float cf = valid ? (float)cnt[f*144+col] : 0.f;
    gacc = fmaf(cf, gcol, gacc);
}

__global__ __launch_bounds__(512, 2) void kfull(
    const float* __restrict__ ch,
    const float* __restrict__ wl1, const float* __restrict__ bl1,
    const float* __restrict__ wg1, const float* __restrict__ bg1,
    const float* __restrict__ wl2, const float* __restrict__ bl2,
    const float* __restrict__ wg2, const float* __restrict__ bg2,
    const float* __restrict__ wl3, const float* __restrict__ bl3,
    const float* __restrict__ wg3, const float* __restrict__ bg3,
    const float* __restrict__ wl4, const float* __restrict__ bl4,
    const float* __restrict__ wg4, const float* __restrict__ bg4,
    const float* __restrict__ wl5, const float* __restrict__ bl5,
    const float* __restrict__ wg5, const float* __restrict__ bg5,
    const float* __restrict__ wl6, const float* __restrict__ bl6,
    const float* __restrict__ wg6, const float* __restrict__ bg6,
    const float* __restrict__ wl7, const float* __restrict__ bl7,
    const float* __restrict__ wg7, const float* __restrict__ bg7,
    const float* __restrict__ wl8, const float* __restrict__ bl8,
    const int* __restrict__ perm3, const int* __restrict__ perm6,
    float* __restrict__ out)
{
    __shared__ float U[14336];     // phase A scratch, then wg6, then wl6
    __shared__ float xBT[9280];    // x3, then x5 (quad layout)
    __shared__ float W45[8192];    // wl4|wg4|wl5|wg5
    __shared__ float W7s[2048];    // compact [64 rows][32 local cols]
    __shared__ float sgf[448];
    __shared__ float g6m[224];
    __shared__ float bl6s[224];
    __shared__ float wl8s[64];
    __shared__ float xms[32];
    __shared__ float gmp[128];
    __shared__ float l8v[1008];
    __shared__ int   pml[1296];
    __shared__ int   cnt[1008];
    __shared__ int   pfn3[144];
    __shared__ float redbuf[8];
    __shared__ float CbS;

    const int tid = threadIdx.x, lane = tid & 63, wid = tid >> 6;
    const int b = blockIdx.x;
    const int wid_u = __builtin_amdgcn_readfirstlane(wid);

    float* f1s   = U;             // 1024
    float* gts   = U + 1024;      // 512
    float* cat3T = U + 9280;      // 3616
    float* f2l   = U + 12896;     // 1024
    float* g3m   = U + 13920;     // 231
    float* xls   = U + 14151;     // 160
    float* xAT   = U;             // 9280 (x4)

    // ---- P0: stage persistent weights + init
    ((float4*)W45)[tid]        = ((const float4*)wl4)[tid];
    ((float4*)W45)[512 + tid]  = ((const float4*)wg4)[tid];
    ((float4*)W45)[1024 + tid] = ((const float4*)wl5)[tid];
    ((float4*)W45)[1536 + tid] = ((const float4*)wg5)[tid];
    {
        int row = tid >> 3, q = tid & 7;
        const float* src = (row < 32) ? (wl7 + row*64) : (wg7 + (row-32)*64);
        *(float4*)&W7s[row*32 + q*4] = *(const float4*)&src[q*4];
    }
    if (tid < 224) bl6s[tid] = bl6[tid];
    if (tid < 64) wl8s[tid] = wl8[tid];
    if (tid < 160) xls[tid] = ch[b*160 + tid];
    if (tid < 144) pfn3[tid] = perm3[tid];
    for (int t = tid; t < 1008; t += 512) cnt[t] = 0;
    __syncthreads();

    // ---- P1: perm6 decode + counts; layer 1
    for (int t = tid; t < 1296; t += 512) { int p = perm6[t]; pml[t] = p; atomicAdd(&cnt[p], 1); }
    #pragma unroll
    for (int it = 0; it < 2; ++it) {
        int t = tid + it*512; int o = t >> 4, n = t & 15;
        int isg = o >= 32, oo = o & 31;
        const float* w = isg ? wg1 : wl1;
        float acc = (isg ? bg1 : bl1)[oo];
        #pragma unroll
        for (int c = 0; c < 10; ++c) acc = fmaf(w[oo*10+c], xls[c*16+n], acc);
        acc = fmaxf(acc, 0.f);
        if (isg) gts[oo*16+n] = acc; else f1s[o*16+n] = acc;
    }
    __syncthreads();
    if (tid < 32) {
        float s = 0.f;
        #pragma unroll
        for (int n = 0; n < 16; ++n) s += gts[tid*16+n];
        s *= (1.f/16.f);
        #pragma unroll
        for (int n = 0; n < 16; ++n) f1s[(32+tid)*16+n] = s;
    }
    __syncthreads();

    // ---- layer 2
    #pragma unroll
    for (int it = 0; it < 2; ++it) {
        int t = tid + it*512; int o = t >> 4, n = t & 15;
        int isg = o >= 32, oo = o & 31;
        const float* w = isg ? wg2 : wl2;
        float acc = (isg ? bg2 : bl2)[oo];
        #pragma unroll
        for (int c = 0; c < 64; ++c) acc = fmaf(w[oo*64+c], f1s[c*16+n], acc);
        acc = fmaxf(acc, 0.f);
        if (isg) gts[oo*16+n] = acc; else f2l[o*16+n] = acc;
    }
    __syncthreads();
    if (tid < 32) {
        float s = 0.f;
        #pragma unroll
        for (int n = 0; n < 16; ++n) s += gts[tid*16+n];
        s *= (1.f/16.f);
        #pragma unroll
        for (int n = 0; n < 16; ++n) f2l[(32+tid)*16+n] = s;
    }
    __syncthreads();

    // ---- layer 3: wave-row scheme (weights from global, wave-uniform rows)
    {
        int n16 = lane & 15, cs = lane >> 4;
        float xr[16];
        #pragma unroll
        for (int i = 0; i < 16; ++i) xr[i] = f2l[cs*256 + i*16 + n16];
        int isg = wid_u >= 4;
        #pragma unroll 2
        for (int k = 0; k < 56; ++k) {
            int r = wid_u*56 + k;
            int rr = isg ? r - 224 : r;
            const float* wrow = (isg ? wg3 : wl3) + rr*64 + cs*16;
            float s0 = 0.f, s1 = 0.f;
            #pragma unroll
            for (int q = 0; q < 4; ++q) {
                float4 w = ((const float4*)wrow)[q];
                if (q & 1) {
                    s1 = fmaf(w.x, xr[q*4+0], s1); s1 = fmaf(w.y, xr[q*4+1], s1);
                    s1 = fmaf(w.z, xr[q*4+2], s1); s1 = fmaf(w.w, xr[q*4+3], s1);
                } else {
                    s0 = fmaf(w.x, xr[q*4+0], s0); s0 = fmaf(w.y, xr[q*4+1], s0);
                    s0 = fmaf(w.z, xr[q*4+2], s0); s0 = fmaf(w.w, xr[q*4+3], s0);
                }
            }
            float s = s0 + s1;
            s += __shfl_xor(s, 16);
            s += __shfl_xor(s, 32);
            s = fmaxf(s + (isg ? bg3 : bl3)[rr], 0.f);
            if (!isg) {
                if (cs == 0) cat3T[n16*226 + rr] = s;
            } else {
                s += __shfl_xor(s, 1); s += __shfl_xor(s, 2);
                s += __shfl_xor(s, 4); s += __shfl_xor(s, 8);
                if (lane == 0) g3m[(rr >> 5)*33 + (rr & 31)] = s * (1.f/16.f);
            }
        }
    }
    __syncthreads();

    // ---- gather into x3 (xBT quad layout)
    for (int t = tid; t < 9216; t += 512) {
        int c4 = t / 576, rem = t - c4*576;
        int col = rem >> 2, ci = rem & 3;
        int c = c4*4 + ci;
        int p3 = pfn3[col]; int pf = p3 >> 4, pn = p3 & 15;
        float v = (c < 32) ? cat3T[pn*226 + pf*32 + c] : g3m[pf*33 + (c - 32)];
        xBT[c4*XQS + col*4 + ci] = v;
    }
    __syncthreads();

    // ---- layers 4 and 5 (weights broadcast from LDS)
    #pragma unroll 1
    for (int L = 0; L < 2; ++L) {
        const float* Ws  = W45 + L*4096;
        const float* blv = L ? bl5 : bl4;
        const float* bgv = L ? bg5 : bg4;
        const float* xin = L ? xAT : xBT;
        float* xout      = L ? xBT : xAT;
        conv64_16_lds(Ws, blv, bgv, xin, xout, lane, wid_u);
        gmean_fill(xout, gmp, xms, tid);
    }
    // xBT = x5 (all 64 rows), xms = x5 global means

    // ---- stage wg6 into U (x4 et al. dead)
    #pragma unroll
    for (int k = 0; k < 7; ++k) ((float4*)U)[tid + k*512] = ((const float4*)wg6)[tid + k*512];
    __syncthreads();

    // ---- g6m: wave-row, weights broadcast from U
    {
        int r0 = wid_u*28;
        int c0 = lane, c1 = 64+lane, c2 = 128+(lane&15);
        #pragma unroll 1
        for (int k = 0; k < 28; ++k) {
            int r = r0 + k;
            const float* wr = U + r*64;
            float bb = bg6[r];
            #pragma unroll
            for (int c4 = 0; c4 < 8; ++c4) {
                float4 w  = *(const float4*)(wr + 32 + c4*4);
                float4 xm = *(const float4*)(xms + c4*4);
                bb = fmaf(w.x, xm.x, bb); bb = fmaf(w.y, xm.y, bb);
                bb = fmaf(w.z, xm.z, bb); bb = fmaf(w.w, xm.w, bb);
            }
            float a0 = bb, a1 = bb, a2 = bb;
            #pragma unroll
            for (int c4 = 0; c4 < 8; ++c4) {
                float4 w  = *(const float4*)(wr + c4*4);
                float4 x0 = *(const float4*)(xBT + c4*XQS + c0*4);
                float4 x1 = *(const float4*)(xBT + c4*XQS + c1*4);
                float4 x2 = *(const float4*)(xBT + c4*XQS + c2*4);
                a0 = fmaf(w.x,x0.x,a0); a0 = fmaf(w.y,x0.y,a0); a0 = fmaf(w.z,x0.z,a0); a0 = fmaf(w.w,x0.w,a0);
                a1 = fmaf(w.x,x1.x,a1); a1 = fmaf(w.y,x1.y,a1); a1 = fmaf(w.z,x1.z,a1); a1 = fmaf(w.w,x1.w,a1);
                a2 = fmaf(w.x,x2.x,a2); a2 = fmaf(w.y,x2.y,a2); a2 = fmaf(w.z,x2.z,a2); a2 = fmaf(w.w,x2.w,a2);
            }
            float s = fmaxf(a0,0.f) + fmaxf(a1,0.f) + ((lane<16) ? fmaxf(a2,0.f) : 0.f);
            s += __shfl_xor(s, 1); s += __shfl_xor(s, 2); s += __shfl_xor(s, 4);
            s += __shfl_xor(s, 8); s += __shfl_xor(s, 16); s += __shfl_xor(s, 32);
            if (lane == 0) g6m[r] = s * (1.f/144.f);
        }
    }
    __syncthreads();

    // ---- stage wl6 into U; compute sgf[f][o7] = bias + W7_gpart . g6m[f]
    #pragma unroll
    for (int k = 0; k < 7; ++k) ((float4*)U)[tid + k*512] = ((const float4*)wl6)[tid + k*512];
    if (tid < 448) {
        int f = wid, o7 = lane;
        const float* wr = (o7 < 32) ? (wl7 + o7*64 + 32) : (wg7 + (o7-32)*64 + 32);
        float s = (o7 < 32) ? bl7[o7] : bg7[o7-32];
        #pragma unroll
        for (int i4 = 0; i4 < 8; ++i4) {
            float4 w = ((const float4*)wr)[i4];
            s = fmaf(w.x, g6m[f*32 + i4*4+0], s);
            s = fmaf(w.y, g6m[f*32 + i4*4+1], s);
            s = fmaf(w.z, g6m[f*32 + i4*4+2], s);
            s = fmaf(w.w, g6m[f*32 + i4*4+3], s);
        }
        sgf[f*64 + o7] = s;
    }
    __syncthreads();

    // ---- main: 16 col-slots. waves 0-6: (f, 64-col halves); wave 7: the 112 tail cols.
    float gacc = 0.f;
    #pragma unroll 1
    for (int it = 0; it < 2; ++it) {
        int f, col; bool valid = true;
        if (wid_u < 7) {
            f = wid_u; col = it*64 + lane;
        } else {
            int ff = it*4 + (lane >> 4);
            valid = ff < 7; f = valid ? ff : 6;
            col = 128 + (lane & 15);
        }
        task_col(f, col, valid, U, W7s, sgf, bl6s, wl8s, cnt, xBT, l8v, gacc);
    }

    // ---- reduce gacc -> Cb
    #pragma unroll
    for (int off = 32; off > 0; off >>= 1) gacc += __shfl_down(gacc, off);
    if (lane == 0) redbuf[wid] = gacc;
    __syncthreads();
    if (tid == 0) {
        float s = 0.f;
        #pragma unroll
        for (int i = 0; i < 8; ++i) s += redbuf[i];
        CbS = bl8[0] + s * (1.f/1296.f);
    }
    __syncthreads();
    float Cb = CbS;
    for (int t = tid; t < 1296; t += 512)
        out[b*1296 + t] = PI_F * (l8v[pml[t]] + Cb);
}

extern "C" void kernel_launch(void* const* d_in, const int* in_sizes, int n_in,
                              void* d_out, int out_size, void* d_ws, size_t ws_size,
                              hipStream_t stream) {
    (void)in_sizes; (void)n_in; (void)out_size; (void)d_ws; (void)ws_size;
    const float* ch  = (const float*)d_in[0];
    const float* wl1 = (const float*)d_in[1];  const float* bl1v = (const float*)d_in[2];
    const float* wg1 = (const float*)d_in[3];  const float* bg1v = (const float*)d_in[4];
    const float* wl2 = (const float*)d_in[5];  const float* bl2v = (const float*)d_in[6];
    const float* wg2 = (const float*)d_in[7];  const float* bg2v = (const float*)d_in[8];
    const float* wl4 = (const float*)d_in[9];  const float* bl4v = (const float*)d_in[10];
    const float* wg4 = (const float*)d_in[11]; const float* bg4v = (const float*)d_in[12];
    const float* wl5 = (const float*)d_in[13]; const float* bl5v = (const float*)d_in[14];
    const float* wg5 = (const float*)d_in[15]; const float* bg5v = (const float*)d_in[16];
    const float* wl7 = (const float*)d_in[17]; const float* bl7v = (const float*)d_in[18];
    const float* wg7 = (const float*)d_in[19]; const float* bg7v = (const float*)d_in[20];
    const float* wl3 = (const float*)d_in[21]; const float* bl3v = (const float*)d_in[22];
    const float* wg3 = (const float*)d_in[23]; const float* bg3v = (const float*)d_in[24];
    const float* wl6 = (const float*)d_in[25]; const float* bl6v = (const float*)d_in[26];
    const float* wg6 = (const float*)d_in[27]; const float* bg6v = (const float*)d_in[28];
    const float* wl8 = (const float*)d_in[29]; const float* bl8v = (const float*)d_in[30];
    const int* perm3 = (const int*)d_in[31];
    const int* perm6 = (const int*)d_in[32];
    float* out = (float*)d_out;

    kfull<<<512, 512, 0, stream>>>(ch,
        wl1, bl1v, wg1, bg1v, wl2, bl2v, wg2, bg2v,
        wl3, bl3v, wg3, bg3v, wl4, bl4v, wg4, bg4v,
        wl5, bl5v, wg5, bg5v, wl6, bl6v, wg6, bg6v,
        wl7, bl7v, wg7, bg7v, wl8, bl8v, perm3, perm6, out);
}

// Round 7
// 313.560 us; speedup vs baseline: 1.3404x; 1.1088x over previous
//
#include <hip/hip_runtime.h>
#include <math.h>

#define PI_F 3.14159265358979323846f
#define XQS 580   // quad-row stride: x[c/4][col*4+(c&3)], 144 cols -> 145 quads padded

// 64->16ch conv (l4/l5): wave-uniform 8-output block, weights broadcast from LDS.
// A (cols 0-63), B (64-127), C (128-143, lanes<16) merged in one weight sweep.
__device__ __forceinline__ void conv64_16_lds(
    const float* __restrict__ Ws,              // LDS: [0..2048) local W, [2048..4096) global W
    const float* __restrict__ blv, const float* __restrict__ bgv,
    const float* __restrict__ xin, float* __restrict__ xout,
    int lane, int ob)
{
    int rb = (ob & 3) * 8;
    const float* W  = Ws + ((ob < 4) ? 0 : 2048);
    const float* bv = (ob < 4) ? blv : bgv;
    int crow = (ob < 4) ? rb : 32 + rb;
    int q0 = crow >> 2;

    int colA = lane, colB = lane + 64, colC = 128 + (lane & 15);
    float accA[8], accB[8], accC[8];
    #pragma unroll
    for (int oi = 0; oi < 8; ++oi) { float bb = bv[rb+oi]; accA[oi] = bb; accB[oi] = bb; accC[oi] = bb; }
    #pragma unroll 4
    for (int c4 = 0; c4 < 16; ++c4) {
        float4 xA = *(const float4*)&xin[c4*XQS + colA*4];
        float4 xB = *(const float4*)&xin[c4*XQS + colB*4];
        float4 xC = *(const float4*)&xin[c4*XQS + colC*4];
        #pragma unroll
        for (int oi = 0; oi < 8; ++oi) {
            float4 w = *(const float4*)&W[(rb+oi)*64 + c4*4];
            accA[oi] = fmaf(w.x, xA.x, accA[oi]); accA[oi] = fmaf(w.y, xA.y, accA[oi]);
            accA[oi] = fmaf(w.z, xA.z, accA[oi]); accA[oi] = fmaf(w.w, xA.w, accA[oi]);
            accB[oi] = fmaf(w.x, xB.x, accB[oi]); accB[oi] = fmaf(w.y, xB.y, accB[oi]);
            accB[oi] = fmaf(w.z, xB.z, accB[oi]); accB[oi] = fmaf(w.w, xB.w, accB[oi]);
            accC[oi] = fmaf(w.x, xC.x, accC[oi]); accC[oi] = fmaf(w.y, xC.y, accC[oi]);
            accC[oi] = fmaf(w.z, xC.z, accC[oi]); accC[oi] = fmaf(w.w, xC.w, accC[oi]);
        }
    }
    *(float4*)&xout[ q0   *XQS + colA*4] = make_float4(fmaxf(accA[0],0.f),fmaxf(accA[1],0.f),fmaxf(accA[2],0.f),fmaxf(accA[3],0.f));
    *(float4*)&xout[(q0+1)*XQS + colA*4] = make_float4(fmaxf(accA[4],0.f),fmaxf(accA[5],0.f),fmaxf(accA[6],0.f),fmaxf(accA[7],0.f));
    *(float4*)&xout[ q0   *XQS + colB*4] = make_float4(fmaxf(accB[0],0.f),fmaxf(accB[1],0.f),fmaxf(accB[2],0.f),fmaxf(accB[3],0.f));
    *(float4*)&xout[(q0+1)*XQS + colB*4] = make_float4(fmaxf(accB[4],0.f),fmaxf(accB[5],0.f),fmaxf(accB[6],0.f),fmaxf(accB[7],0.f));
    if (lane < 16) {
        *(float4*)&xout[ q0   *XQS + colC*4] = make_float4(fmaxf(accC[0],0.f),fmaxf(accC[1],0.f),fmaxf(accC[2],0.f),fmaxf(accC[3],0.f));
        *(float4*)&xout[(q0+1)*XQS + colC*4] = make_float4(fmaxf(accC[4],0.f),fmaxf(accC[5],0.f),fmaxf(accC[6],0.f),fmaxf(accC[7],0.f));
    }
}

__device__ __forceinline__ void gmean_fill(float* __restrict__ xout, float* __restrict__ gmp,
                                           float* __restrict__ xms, int tid)
{
    __syncthreads();
    if (tid < 128) {
        int j = tid >> 2, q = tid & 3;
        int cc = 32 + j; int qr = cc >> 2, cb = cc & 3;
        float s = 0.f;
        for (int col = q*36; col < q*36+36; ++col) s += xout[qr*XQS + col*4 + cb];
        gmp[tid] = s;
    }
    __syncthreads();
    if (tid < 32) xms[tid] = (gmp[tid*4]+gmp[tid*4+1]+gmp[tid*4+2]+gmp[tid*4+3]) * (1.f/144.f);
    __syncthreads();
    for (int t = tid; t < 4608; t += 512) {
        int col = t >> 5, j = t & 31;
        int cc = 32 + j;
        xout[(cc>>2)*XQS + col*4 + (cc&3)] = xms[j];
    }
    __syncthreads();
}

__global__ __launch_bounds__(512, 2) void kfull(
    const float* __restrict__ ch,
    const float* __restrict__ wl1, const float* __restrict__ bl1,
    const float* __restrict__ wg1, const float* __restrict__ bg1,
    const float* __restrict__ wl2, const float* __restrict__ bl2,
    const float* __restrict__ wg2, const float* __restrict__ bg2,
    const float* __restrict__ wl3, const float* __restrict__ bl3,
    const float* __restrict__ wg3, const float* __restrict__ bg3,
    const float* __restrict__ wl4, const float* __restrict__ bl4,
    const float* __restrict__ wg4, const float* __restrict__ bg4,
    const float* __restrict__ wl5, const float* __restrict__ bl5,
    const float* __restrict__ wg5, const float* __restrict__ bg5,
    const float* __restrict__ wl6, const float* __restrict__ bl6,
    const float* __restrict__ wg6, const float* __restrict__ bg6,
    const float* __restrict__ wl7, const float* __restrict__ bl7,
    const float* __restrict__ wg7, const float* __restrict__ bg7,
    const float* __restrict__ wl8, const float* __restrict__ bl8,
    const int* __restrict__ perm3, const int* __restrict__ perm6,
    float* __restrict__ out)
{
    __shared__ float U[14336];     // phase A scratch, then wg6, then wl6
    __shared__ float xBT[9280];    // x3, then x5 (quad layout)
    __shared__ float W45[8192];    // wl4|wg4|wl5|wg5
    __shared__ float W7s[2048];    // compact [64 rows][32 local cols]
    __shared__ float sgf[448];
    __shared__ float g6m[224];
    __shared__ float bl6s[224];
    __shared__ float wl8s[64];
    __shared__ float xms[32];
    __shared__ float gmp[128];
    __shared__ float l8v[1008];
    __shared__ int   pml[1296];
    __shared__ int   cnt[1008];
    __shared__ int   pfn3[144];
    __shared__ float redbuf[8];
    __shared__ float CbS;

    const int tid = threadIdx.x, lane = tid & 63, wid = tid >> 6;
    const int b = blockIdx.x;
    const int wid_u = __builtin_amdgcn_readfirstlane(wid);

    float* f1s   = U;             // 1024
    float* gts   = U + 1024;      // 512
    float* cat3T = U + 9280;      // 3616
    float* f2l   = U + 12896;     // 1024
    float* g3m   = U + 13920;     // 231
    float* xls   = U + 14151;     // 160
    float* xAT   = U;             // 9280 (x4)

    // ---- P0: stage persistent weights + init
    ((float4*)W45)[tid]        = ((const float4*)wl4)[tid];
    ((float4*)W45)[512 + tid]  = ((const float4*)wg4)[tid];
    ((float4*)W45)[1024 + tid] = ((const float4*)wl5)[tid];
    ((float4*)W45)[1536 + tid] = ((const float4*)wg5)[tid];
    {
        int row = tid >> 3, q = tid & 7;
        const float* src = (row < 32) ? (wl7 + row*64) : (wg7 + (row-32)*64);
        *(float4*)&W7s[row*32 + q*4] = *(const float4*)&src[q*4];
    }
    if (tid < 224) bl6s[tid] = bl6[tid];
    if (tid < 64) wl8s[tid] = wl8[tid];
    if (tid < 160) xls[tid] = ch[b*160 + tid];
    if (tid < 144) pfn3[tid] = perm3[tid];
    for (int t = tid; t < 1008; t += 512) cnt[t] = 0;
    __syncthreads();

    // ---- P1: perm6 decode + counts; layer 1
    for (int t = tid; t < 1296; t += 512) { int p = perm6[t]; pml[t] = p; atomicAdd(&cnt[p], 1); }
    #pragma unroll
    for (int it = 0; it < 2; ++it) {
        int t = tid + it*512; int o = t >> 4, n = t & 15;
        int isg = o >= 32, oo = o & 31;
        const float* w = isg ? wg1 : wl1;
        float acc = (isg ? bg1 : bl1)[oo];
        #pragma unroll
        for (int c = 0; c < 10; ++c) acc = fmaf(w[oo*10+c], xls[c*16+n], acc);
        acc = fmaxf(acc, 0.f);
        if (isg) gts[oo*16+n] = acc; else f1s[o*16+n] = acc;
    }
    __syncthreads();
    if (tid < 32) {
        float s = 0.f;
        #pragma unroll
        for (int n = 0; n < 16; ++n) s += gts[tid*16+n];
        s *= (1.f/16.f);
        #pragma unroll
        for (int n = 0; n < 16; ++n) f1s[(32+tid)*16+n] = s;
    }
    __syncthreads();

    // ---- layer 2
    #pragma unroll
    for (int it = 0; it < 2; ++it) {
        int t = tid + it*512; int o = t >> 4, n = t & 15;
        int isg = o >= 32, oo = o & 31;
        const float* w = isg ? wg2 : wl2;
        float acc = (isg ? bg2 : bl2)[oo];
        #pragma unroll
        for (int c = 0; c < 64; ++c) acc = fmaf(w[oo*64+c], f1s[c*16+n], acc);
        acc = fmaxf(acc, 0.f);
        if (isg) gts[oo*16+n] = acc; else f2l[o*16+n] = acc;
    }
    __syncthreads();
    if (tid < 32) {
        float s = 0.f;
        #pragma unroll
        for (int n = 0; n < 16; ++n) s += gts[tid*16+n];
        s *= (1.f/16.f);
        #pragma unroll
        for (int n = 0; n < 16; ++n) f2l[(32+tid)*16+n] = s;
    }
    __syncthreads();

    // ---- layer 3: wave-row scheme (weights from global, wave-uniform rows)
    {
        int n16 = lane & 15, cs = lane >> 4;
        float xr[16];
        #pragma unroll
        for (int i = 0; i < 16; ++i) xr[i] = f2l[cs*256 + i*16 + n16];
        int isg = wid_u >= 4;
        #pragma unroll 2
        for (int k = 0; k < 56; ++k) {
            int r = wid_u*56 + k;
            int rr = isg ? r - 224 : r;
            const float* wrow = (isg ? wg3 : wl3) + rr*64 + cs*16;
            float s0 = 0.f, s1 = 0.f;
            #pragma unroll
            for (int q = 0; q < 4; ++q) {
                float4 w = ((const float4*)wrow)[q];
                if (q & 1) {
                    s1 = fmaf(w.x, xr[q*4+0], s1); s1 = fmaf(w.y, xr[q*4+1], s1);
                    s1 = fmaf(w.z, xr[q*4+2], s1); s1 = fmaf(w.w, xr[q*4+3], s1);
                } else {
                    s0 = fmaf(w.x, xr[q*4+0], s0); s0 = fmaf(w.y, xr[q*4+1], s0);
                    s0 = fmaf(w.z, xr[q*4+2], s0); s0 = fmaf(w.w, xr[q*4+3], s0);
                }
            }
            float s = s0 + s1;
            s += __shfl_xor(s, 16);
            s += __shfl_xor(s, 32);
            s = fmaxf(s + (isg ? bg3 : bl3)[rr], 0.f);
            if (!isg) {
                if (cs == 0) cat3T[n16*226 + rr] = s;
            } else {
                s += __shfl_xor(s, 1); s += __shfl_xor(s, 2);
                s += __shfl_xor(s, 4); s += __shfl_xor(s, 8);
                if (lane == 0) g3m[(rr >> 5)*33 + (rr & 31)] = s * (1.f/16.f);
            }
        }
    }
    __syncthreads();

    // ---- gather into x3 (xBT quad layout)
    for (int t = tid; t < 9216; t += 512) {
        int c4 = t / 576, rem = t - c4*576;
        int col = rem >> 2, ci = rem & 3;
        int c = c4*4 + ci;
        int p3 = pfn3[col]; int pf = p3 >> 4, pn = p3 & 15;
        float v = (c < 32) ? cat3T[pn*226 + pf*32 + c] : g3m[pf*33 + (c - 32)];
        xBT[c4*XQS + col*4 + ci] = v;
    }
    __syncthreads();

    // ---- layers 4 and 5 (weights broadcast from LDS)
    #pragma unroll 1
    for (int L = 0; L < 2; ++L) {
        const float* Ws  = W45 + L*4096;
        const float* blv = L ? bl5 : bl4;
        const float* bgv = L ? bg5 : bg4;
        const float* xin = L ? xAT : xBT;
        float* xout      = L ? xBT : xAT;
        conv64_16_lds(Ws, blv, bgv, xin, xout, lane, wid_u);
        gmean_fill(xout, gmp, xms, tid);
    }
    // xBT = x5 (all 64 rows), xms = x5 global means

    // ---- stage wg6 into U (x4 et al. dead)
    #pragma unroll
    for (int k = 0; k < 7; ++k) ((float4*)U)[tid + k*512] = ((const float4*)wg6)[tid + k*512];
    __syncthreads();

    // ---- g6m: wave-row, weights broadcast from U; x cached in registers
    {
        int r0 = wid_u*28;
        int c0 = lane, c1 = 64+lane, c2 = 128+(lane&15);
        float4 xc0[8], xc1[8], xc2[8], xmq[8];
        #pragma unroll
        for (int c4 = 0; c4 < 8; ++c4) {
            xc0[c4] = *(const float4*)(xBT + c4*XQS + c0*4);
            xc1[c4] = *(const float4*)(xBT + c4*XQS + c1*4);
            xc2[c4] = *(const float4*)(xBT + c4*XQS + c2*4);
            xmq[c4] = *(const float4*)(xms + c4*4);
        }
        #pragma unroll 1
        for (int k = 0; k < 28; ++k) {
            int r = r0 + k;
            const float* wr = U + r*64;
            float bb = bg6[r];
            #pragma unroll
            for (int c4 = 0; c4 < 8; ++c4) {
                float4 w = *(const float4*)(wr + 32 + c4*4);
                bb = fmaf(w.x, xmq[c4].x, bb); bb = fmaf(w.y, xmq[c4].y, bb);
                bb = fmaf(w.z, xmq[c4].z, bb); bb = fmaf(w.w, xmq[c4].w, bb);
            }
            float a0 = bb, a1 = bb, a2 = bb;
            #pragma unroll
            for (int c4 = 0; c4 < 8; ++c4) {
                float4 w = *(const float4*)(wr + c4*4);
                a0 = fmaf(w.x,xc0[c4].x,a0); a0 = fmaf(w.y,xc0[c4].y,a0); a0 = fmaf(w.z,xc0[c4].z,a0); a0 = fmaf(w.w,xc0[c4].w,a0);
                a1 = fmaf(w.x,xc1[c4].x,a1); a1 = fmaf(w.y,xc1[c4].y,a1); a1 = fmaf(w.z,xc1[c4].z,a1); a1 = fmaf(w.w,xc1[c4].w,a1);
                a2 = fmaf(w.x,xc2[c4].x,a2); a2 = fmaf(w.y,xc2[c4].y,a2); a2 = fmaf(w.z,xc2[c4].z,a2); a2 = fmaf(w.w,xc2[c4].w,a2);
            }
            float s = fmaxf(a0,0.f) + fmaxf(a1,0.f) + ((lane<16) ? fmaxf(a2,0.f) : 0.f);
            s += __shfl_xor(s, 1); s += __shfl_xor(s, 2); s += __shfl_xor(s, 4);
            s += __shfl_xor(s, 8); s += __shfl_xor(s, 16); s += __shfl_xor(s, 32);
            if (lane == 0) g6m[r] = s * (1.f/144.f);
        }
    }
    __syncthreads();

    // ---- stage wl6 into U; compute sgf[f][o7] = bias + W7_gpart . g6m[f]
    #pragma unroll
    for (int k = 0; k < 7; ++k) ((float4*)U)[tid + k*512] = ((const float4*)wl6)[tid + k*512];
    if (tid < 448) {
        int f = wid, o7 = lane;
        const float* wr = (o7 < 32) ? (wl7 + o7*64 + 32) : (wg7 + (o7-32)*64 + 32);
        float s = (o7 < 32) ? bl7[o7] : bg7[o7-32];
        #pragma unroll
        for (int i4 = 0; i4 < 8; ++i4) {
            float4 w = ((const float4*)wr)[i4];
            s = fmaf(w.x, g6m[f*32 + i4*4+0], s);
            s = fmaf(w.y, g6m[f*32 + i4*4+1], s);
            s = fmaf(w.z, g6m[f*32 + i4*4+2], s);
            s = fmaf(w.w, g6m[f*32 + i4*4+3], s);
        }
        sgf[f*64 + o7] = s;
    }
    __syncthreads();

    // ---- main: 63 tasks (f 0..6 x colgroup 0..8), 8 lanes/task, 2 cols/lane.
    //      One W6/W7 sweep per wave; <=2 distinct f per wave -> 2-way multicast reads.
    float gacc = 0.f;
    {
        int t = 8*wid_u + (lane >> 3);
        bool valid = t < 63;
        int tt = valid ? t : 62;
        int f = tt / 9;
        int g = tt - f*9;
        int colA = g*16 + (lane & 7);
        int colB = colA + 8;

        float4 xqA[16], xqB[16];
        #pragma unroll
        for (int c4 = 0; c4 < 16; ++c4) {
            xqA[c4] = *(const float4*)(xBT + c4*XQS + colA*4);
            xqB[c4] = *(const float4*)(xBT + c4*XQS + colB*4);
        }
        const float* wf = U + f*2048;
        const float* bf = bl6s + f*32;
        float accA[32], accB[32];
        #pragma unroll
        for (int o = 0; o < 32; ++o) {
            float bb = bf[o];
            float sA = bb, sB = bb;
            const float* w0 = wf + o*64;
            #pragma unroll
            for (int c4 = 0; c4 < 16; ++c4) {
                float4 w = *(const float4*)(w0 + c4*4);
                sA = fmaf(w.x, xqA[c4].x, sA); sA = fmaf(w.y, xqA[c4].y, sA);
                sA = fmaf(w.z, xqA[c4].z, sA); sA = fmaf(w.w, xqA[c4].w, sA);
                sB = fmaf(w.x, xqB[c4].x, sB); sB = fmaf(w.y, xqB[c4].y, sB);
                sB = fmaf(w.z, xqB[c4].z, sB); sB = fmaf(w.w, xqB[c4].w, sB);
            }
            accA[o] = fmaxf(sA, 0.f);
            accB[o] = fmaxf(sB, 0.f);
        }
        const float* sgff = sgf + f*64;
        float l8aA = 0.f, l8aB = 0.f, gA = 0.f, gB = 0.f;
        #pragma unroll 1
        for (int o7 = 0; o7 < 32; ++o7) {              // l7 local rows
            float s0 = sgff[o7];
            float sA = s0, sB = s0;
            const float* wr = W7s + o7*32;
            #pragma unroll
            for (int q = 0; q < 8; ++q) {
                float4 w = *(const float4*)(wr + q*4);
                sA = fmaf(w.x, accA[q*4+0], sA); sA = fmaf(w.y, accA[q*4+1], sA);
                sA = fmaf(w.z, accA[q*4+2], sA); sA = fmaf(w.w, accA[q*4+3], sA);
                sB = fmaf(w.x, accB[q*4+0], sB); sB = fmaf(w.y, accB[q*4+1], sB);
                sB = fmaf(w.z, accB[q*4+2], sB); sB = fmaf(w.w, accB[q*4+3], sB);
            }
            float wgt = wl8s[o7];
            l8aA = fmaf(wgt, fmaxf(sA, 0.f), l8aA);
            l8aB = fmaf(wgt, fmaxf(sB, 0.f), l8aB);
        }
        #pragma unroll 1
        for (int o7 = 0; o7 < 32; ++o7) {              // l7 global rows
            float s0 = sgff[32+o7];
            float sA = s0, sB = s0;
            const float* wr = W7s + (32+o7)*32;
            #pragma unroll
            for (int q = 0; q < 8; ++q) {
                float4 w = *(const float4*)(wr + q*4);
                sA = fmaf(w.x, accA[q*4+0], sA); sA = fmaf(w.y, accA[q*4+1], sA);
                sA = fmaf(w.z, accA[q*4+2], sA); sA = fmaf(w.w, accA[q*4+3], sA);
                sB = fmaf(w.x, accB[q*4+0], sB); sB = fmaf(w.y, accB[q*4+1], sB);
                sB = fmaf(w.z, accB[q*4+2], sB); sB = fmaf(w.w, accB[q*4+3], sB);
            }
            float wgt = wl8s[32+o7];
            gA = fmaf(wgt, fmaxf(sA, 0.f), gA);
            gB = fmaf(wgt, fmaxf(sB, 0.f), gB);
        }
        if (valid) {
            l8v[f*144 + colA] = l8aA;
            l8v[f*144 + colB] = l8aB;
            gacc = fmaf((float)cnt[f*144 + colA], gA, gacc);
            gacc = fmaf((float)cnt[f*144 + colB], gB, gacc);
        }
    }

    // ---- reduce gacc -> Cb
    #pragma unroll
    for (int off = 32; off > 0; off >>= 1) gacc += __shfl_down(gacc, off);
    if (lane == 0) redbuf[wid] = gacc;
    __syncthreads();
    if (tid == 0) {
        float s = 0.f;
        #pragma unroll
        for (int i = 0; i < 8; ++i) s += redbuf[i];
        CbS = bl8[0] + s * (1.f/1296.f);
    }
    __syncthreads();
    float Cb = CbS;
    for (int t = tid; t < 1296; t += 512)
        out[b*1296 + t] = PI_F * (l8v[pml[t]] + Cb);
}

extern "C" void kernel_launch(void* const* d_in, const int* in_sizes, int n_in,
                              void* d_out, int out_size, void* d_ws, size_t ws_size,
                              hipStream_t stream) {
    (void)in_sizes; (void)n_in; (void)out_size; (void)d_ws; (void)ws_size;
    const float* ch  = (const float*)d_in[0];
    const float* wl1 = (const float*)d_in[1];  const float* bl1v = (const float*)d_in[2];
    const float* wg1 = (const float*)d_in[3];  const float* bg1v = (const float*)d_in[4];
    const float* wl2 = (const float*)d_in[5];  const float* bl2v = (const float*)d_in[6];
    const float* wg2 = (const float*)d_in[7];  const float* bg2v = (const float*)d_in[8];
    const float* wl4 = (const float*)d_in[9];  const float* bl4v = (const float*)d_in[10];
    const float* wg4 = (const float*)d_in[11]; const float* bg4v = (const float*)d_in[12];
    const float* wl5 = (const float*)d_in[13]; const float* bl5v = (const float*)d_in[14];
    const float* wg5 = (const float*)d_in[15]; const float* bg5v = (const float*)d_in[16];
    const float* wl7 = (const float*)d_in[17]; const float* bl7v = (const float*)d_in[18];
    const float* wg7 = (const float*)d_in[19]; const float* bg7v = (const float*)d_in[20];
    const float* wl3 = (const float*)d_in[21]; const float* bl3v = (const float*)d_in[22];
    const float* wg3 = (const float*)d_in[23]; const float* bg3v = (const float*)d_in[24];
    const float* wl6 = (const float*)d_in[25]; const float* bl6v = (const float*)d_in[26];
    const float* wg6 = (const float*)d_in[27]; const float* bg6v = (const float*)d_in[28];
    const float* wl8 = (const float*)d_in[29]; const float* bl8v = (const float*)d_in[30];
    const int* perm3 = (const int*)d_in[31];
    const int* perm6 = (const int*)d_in[32];
    float* out = (float*)d_out;

    kfull<<<512, 512, 0, stream>>>(ch,
        wl1, bl1v, wg1, bg1v, wl2, bl2v, wg2, bg2v,
        wl3, bl3v, wg3, bg3v, wl4, bl4v, wg4, bg4v,
        wl5, bl5v, wg5, bg5v, wl6, bl6v, wg6, bg6v,
        wl7, bl7v, wg7, bg7v, wl8, bl8v, perm3, perm6, out);
}

// Round 8
// 265.133 us; speedup vs baseline: 1.5852x; 1.1827x over previous
//
#include <hip/hip_runtime.h>
#include <math.h>

#define PI_F 3.14159265358979323846f
#define XQS 580     // quad-row stride (floats)
#define XB_B 4640   // per-batch x size: 8 quad-rows x 580

// 64->16ch conv, K=32 local half + precomputed mean-part. 2 batches, 3 cols/lane each.
// Waves 0-3: local outputs (write xout). Waves 4-7: global outputs (reduce -> xmsOut).
__device__ __forceinline__ void conv32K(
    const float* __restrict__ Wh,      // LDS [64 rows][32]
    const float* __restrict__ xin,     // LDS, batch0 at +0, batch1 at +XB_B
    float* __restrict__ xout,
    const float* __restrict__ m0, const float* __restrict__ m1, const float* __restrict__ m2,
    const float* __restrict__ m3, const float* __restrict__ m4, const float* __restrict__ m5,
    float* __restrict__ xmsOut, int lane, int wid_u)
{
    int isg = wid_u >= 4, rb = (wid_u & 3) * 8;
    int rowbase = isg * 32 + rb;
    int cA = lane, cB = 64 + lane, cC = 128 + (lane & 15);
    float a0[8], a1[8], a2[8], a3[8], a4[8], a5[8];
    #pragma unroll
    for (int i = 0; i < 8; ++i) { a0[i]=0.f;a1[i]=0.f;a2[i]=0.f;a3[i]=0.f;a4[i]=0.f;a5[i]=0.f; }
    #pragma unroll 1
    for (int kb = 0; kb < 4; ++kb) {
        int ca = kb*2, cb = kb*2 + 1;
        float4 xA0 = *(const float4*)&xin[ca*XQS + cA*4];
        float4 xA1 = *(const float4*)&xin[cb*XQS + cA*4];
        float4 xB0 = *(const float4*)&xin[ca*XQS + cB*4];
        float4 xB1 = *(const float4*)&xin[cb*XQS + cB*4];
        float4 xC0 = *(const float4*)&xin[ca*XQS + cC*4];
        float4 xC1 = *(const float4*)&xin[cb*XQS + cC*4];
        float4 yA0 = *(const float4*)&xin[XB_B + ca*XQS + cA*4];
        float4 yA1 = *(const float4*)&xin[XB_B + cb*XQS + cA*4];
        float4 yB0 = *(const float4*)&xin[XB_B + ca*XQS + cB*4];
        float4 yB1 = *(const float4*)&xin[XB_B + cb*XQS + cB*4];
        float4 yC0 = *(const float4*)&xin[XB_B + ca*XQS + cC*4];
        float4 yC1 = *(const float4*)&xin[XB_B + cb*XQS + cC*4];
        const float* wb = Wh + rowbase*32 + kb*8;
        #pragma unroll
        for (int oi = 0; oi < 8; ++oi) {
            float4 w0 = *(const float4*)&wb[oi*32];
            float4 w1 = *(const float4*)&wb[oi*32 + 4];
            a0[oi] = fmaf(w0.x,xA0.x,a0[oi]); a0[oi] = fmaf(w0.y,xA0.y,a0[oi]);
            a0[oi] = fmaf(w0.z,xA0.z,a0[oi]); a0[oi] = fmaf(w0.w,xA0.w,a0[oi]);
            a0[oi] = fmaf(w1.x,xA1.x,a0[oi]); a0[oi] = fmaf(w1.y,xA1.y,a0[oi]);
            a0[oi] = fmaf(w1.z,xA1.z,a0[oi]); a0[oi] = fmaf(w1.w,xA1.w,a0[oi]);
            a1[oi] = fmaf(w0.x,xB0.x,a1[oi]); a1[oi] = fmaf(w0.y,xB0.y,a1[oi]);
            a1[oi] = fmaf(w0.z,xB0.z,a1[oi]); a1[oi] = fmaf(w0.w,xB0.w,a1[oi]);
            a1[oi] = fmaf(w1.x,xB1.x,a1[oi]); a1[oi] = fmaf(w1.y,xB1.y,a1[oi]);
            a1[oi] = fmaf(w1.z,xB1.z,a1[oi]); a1[oi] = fmaf(w1.w,xB1.w,a1[oi]);
            a2[oi] = fmaf(w0.x,xC0.x,a2[oi]); a2[oi] = fmaf(w0.y,xC0.y,a2[oi]);
            a2[oi] = fmaf(w0.z,xC0.z,a2[oi]); a2[oi] = fmaf(w0.w,xC0.w,a2[oi]);
            a2[oi] = fmaf(w1.x,xC1.x,a2[oi]); a2[oi] = fmaf(w1.y,xC1.y,a2[oi]);
            a2[oi] = fmaf(w1.z,xC1.z,a2[oi]); a2[oi] = fmaf(w1.w,xC1.w,a2[oi]);
            a3[oi] = fmaf(w0.x,yA0.x,a3[oi]); a3[oi] = fmaf(w0.y,yA0.y,a3[oi]);
            a3[oi] = fmaf(w0.z,yA0.z,a3[oi]); a3[oi] = fmaf(w0.w,yA0.w,a3[oi]);
            a3[oi] = fmaf(w1.x,yA1.x,a3[oi]); a3[oi] = fmaf(w1.y,yA1.y,a3[oi]);
            a3[oi] = fmaf(w1.z,yA1.z,a3[oi]); a3[oi] = fmaf(w1.w,yA1.w,a3[oi]);
            a4[oi] = fmaf(w0.x,yB0.x,a4[oi]); a4[oi] = fmaf(w0.y,yB0.y,a4[oi]);
            a4[oi] = fmaf(w0.z,yB0.z,a4[oi]); a4[oi] = fmaf(w0.w,yB0.w,a4[oi]);
            a4[oi] = fmaf(w1.x,yB1.x,a4[oi]); a4[oi] = fmaf(w1.y,yB1.y,a4[oi]);
            a4[oi] = fmaf(w1.z,yB1.z,a4[oi]); a4[oi] = fmaf(w1.w,yB1.w,a4[oi]);
            a5[oi] = fmaf(w0.x,yC0.x,a5[oi]); a5[oi] = fmaf(w0.y,yC0.y,a5[oi]);
            a5[oi] = fmaf(w0.z,yC0.z,a5[oi]); a5[oi] = fmaf(w0.w,yC0.w,a5[oi]);
            a5[oi] = fmaf(w1.x,yC1.x,a5[oi]); a5[oi] = fmaf(w1.y,yC1.y,a5[oi]);
            a5[oi] = fmaf(w1.z,yC1.z,a5[oi]); a5[oi] = fmaf(w1.w,yC1.w,a5[oi]);
        }
    }
    #pragma unroll
    for (int oi = 0; oi < 8; ++oi) {
        int row = rowbase + oi;
        a0[oi] = fmaxf(a0[oi] + m0[row], 0.f);
        a1[oi] = fmaxf(a1[oi] + m1[row], 0.f);
        a2[oi] = fmaxf(a2[oi] + m2[row], 0.f);
        a3[oi] = fmaxf(a3[oi] + m3[row], 0.f);
        a4[oi] = fmaxf(a4[oi] + m4[row], 0.f);
        a5[oi] = fmaxf(a5[oi] + m5[row], 0.f);
    }
    if (!isg) {
        int q0 = rb >> 2;
        *(float4*)&xout[ q0   *XQS + cA*4] = make_float4(a0[0],a0[1],a0[2],a0[3]);
        *(float4*)&xout[(q0+1)*XQS + cA*4] = make_float4(a0[4],a0[5],a0[6],a0[7]);
        *(float4*)&xout[ q0   *XQS + cB*4] = make_float4(a1[0],a1[1],a1[2],a1[3]);
        *(float4*)&xout[(q0+1)*XQS + cB*4] = make_float4(a1[4],a1[5],a1[6],a1[7]);
        *(float4*)&xout[XB_B +  q0   *XQS + cA*4] = make_float4(a3[0],a3[1],a3[2],a3[3]);
        *(float4*)&xout[XB_B + (q0+1)*XQS + cA*4] = make_float4(a3[4],a3[5],a3[6],a3[7]);
        *(float4*)&xout[XB_B +  q0   *XQS + cB*4] = make_float4(a4[0],a4[1],a4[2],a4[3]);
        *(float4*)&xout[XB_B + (q0+1)*XQS + cB*4] = make_float4(a4[4],a4[5],a4[6],a4[7]);
        if (lane < 16) {
            *(float4*)&xout[ q0   *XQS + cC*4] = make_float4(a2[0],a2[1],a2[2],a2[3]);
            *(float4*)&xout[(q0+1)*XQS + cC*4] = make_float4(a2[4],a2[5],a2[6],a2[7]);
            *(float4*)&xout[XB_B +  q0   *XQS + cC*4] = make_float4(a5[0],a5[1],a5[2],a5[3]);
            *(float4*)&xout[XB_B + (q0+1)*XQS + cC*4] = make_float4(a5[4],a5[5],a5[6],a5[7]);
        }
    } else {
        #pragma unroll
        for (int oi = 0; oi < 8; ++oi) {
            float s0 = a0[oi] + a1[oi] + ((lane < 16) ? a2[oi] : 0.f);
            float s1 = a3[oi] + a4[oi] + ((lane < 16) ? a5[oi] : 0.f);
            #pragma unroll
            for (int off = 1; off < 64; off <<= 1) { s0 += __shfl_xor(s0, off); s1 += __shfl_xor(s1, off); }
            if (lane == 0) { xmsOut[rb + oi] = s0 * (1.f/144.f); xmsOut[32 + rb + oi] = s1 * (1.f/144.f); }
        }
    }
}

__global__ __launch_bounds__(512, 2) void kfull(
    const float* __restrict__ ch,
    const float* __restrict__ wl1, const float* __restrict__ bl1,
    const float* __restrict__ wg1, const float* __restrict__ bg1,
    const float* __restrict__ wl2, const float* __restrict__ bl2,
    const float* __restrict__ wg2, const float* __restrict__ bg2,
    const float* __restrict__ wl3, const float* __restrict__ bl3,
    const float* __restrict__ wg3, const float* __restrict__ bg3,
    const float* __restrict__ wl4, const float* __restrict__ bl4,
    const float* __restrict__ wg4, const float* __restrict__ bg4,
    const float* __restrict__ wl5, const float* __restrict__ bl5,
    const float* __restrict__ wg5, const float* __restrict__ bg5,
    const float* __restrict__ wl6, const float* __restrict__ bl6,
    const float* __restrict__ wg6, const float* __restrict__ bg6,
    const float* __restrict__ wl7, const float* __restrict__ bl7,
    const float* __restrict__ wg7, const float* __restrict__ bg7,
    const float* __restrict__ wl8, const float* __restrict__ bl8,
    const int* __restrict__ perm3, const int* __restrict__ perm6,
    float* __restrict__ out)
{
    __shared__ float U[14336];     // phase-A scratch -> x4 -> wg6h|wl6h
    __shared__ float xB[9280];     // [2 batches][8 quad-rows] : x3 then x5 (local rows)
    __shared__ float W45h[4096];   // [2 layers][64 rows][32] local-K halves
    __shared__ float W7s[2048];    // [64 rows][32] local-K half
    __shared__ float mp4[896];     // [b][pf][64]   bias + Wg-K . g3m[pf]
    __shared__ float mp5[128];     // [b][64]       bias + Wg-K . xms4
    __shared__ float mp6[448];     // [b][f*32+o]   bias + wl6g-K . xms5
    __shared__ float mpg6[448];    // [b][224]      bias + wg6g-K . xms5
    __shared__ float sgf[896];     // [b][f*64+o7]  bias + W7g-K . g6m[f]
    __shared__ float g6m[448];     // [b][224]
    __shared__ float wl8s[64];
    __shared__ float xms4[64];     // [b][32]
    __shared__ float xms5[64];
    __shared__ float l8v[2016];    // [b][1008]
    __shared__ int   pml[1296];
    __shared__ int   cnt[1008];
    __shared__ int   pfn3[144];
    __shared__ float redbuf[16];
    __shared__ float CbS[2];

    const int tid = threadIdx.x, lane = tid & 63, wid = tid >> 6;
    const int blk = blockIdx.x;
    const int wid_u = __builtin_amdgcn_readfirstlane(wid);

    float* f1s   = U;             // 2048
    float* gts   = U + 2048;      // 1024
    float* f2l   = U + 3072;      // 2048
    float* cat3T = U + 5120;      // 7232
    float* g3m   = U + 12352;     // 462
    float* xls   = U + 12814;     // 320
    float* x4s   = U;             // alias: 9280
    float* wg6h  = U;             // alias: 7168
    float* wl6h  = U + 7168;      // alias: 7168

    // ---- P0: stage persistent weights + init
    for (int t = tid; t < 1024; t += 512) {
        int l = t >> 9, rem = t & 511;
        int row = rem >> 3, q = rem & 7;
        const float* src = l ? ((row < 32) ? wl5 + row*64 : wg5 + (row-32)*64)
                             : ((row < 32) ? wl4 + row*64 : wg4 + (row-32)*64);
        *(float4*)&W45h[l*2048 + row*32 + q*4] = *(const float4*)&src[q*4];
    }
    {
        int row = tid >> 3, q = tid & 7;
        const float* src = (row < 32) ? (wl7 + row*64) : (wg7 + (row-32)*64);
        *(float4*)&W7s[row*32 + q*4] = *(const float4*)&src[q*4];
    }
    if (tid < 64) wl8s[tid] = wl8[tid];
    if (tid < 320) { int b = tid >= 160, i = tid - b*160; xls[b*160 + i] = ch[(2*blk + b)*160 + i]; }
    if (tid < 144) pfn3[tid] = perm3[tid];
    for (int t = tid; t < 1008; t += 512) cnt[t] = 0;
    __syncthreads();

    // ---- perm6 decode + counts; layer 1 (2 batches)
    for (int t = tid; t < 1296; t += 512) { int p = perm6[t]; pml[t] = p; atomicAdd(&cnt[p], 1); }
    #pragma unroll
    for (int it = 0; it < 4; ++it) {
        int t = tid + it*512; int b = t >> 10, o = (t >> 4) & 63, n = t & 15;
        int isg = o >= 32, oo = o & 31;
        const float* w = isg ? wg1 : wl1;
        float acc = (isg ? bg1 : bl1)[oo];
        #pragma unroll
        for (int c = 0; c < 10; ++c) acc = fmaf(w[oo*10+c], xls[b*160 + c*16+n], acc);
        acc = fmaxf(acc, 0.f);
        if (isg) gts[b*512 + oo*16+n] = acc; else f1s[b*1024 + o*16+n] = acc;
    }
    __syncthreads();
    if (tid < 64) {
        int b = tid >> 5, j = tid & 31;
        float s = 0.f;
        #pragma unroll
        for (int n = 0; n < 16; ++n) s += gts[b*512 + j*16+n];
        s *= (1.f/16.f);
        #pragma unroll
        for (int n = 0; n < 16; ++n) f1s[b*1024 + (32+j)*16+n] = s;
    }
    __syncthreads();

    // ---- layer 2
    #pragma unroll
    for (int it = 0; it < 4; ++it) {
        int t = tid + it*512; int b = t >> 10, o = (t >> 4) & 63, n = t & 15;
        int isg = o >= 32, oo = o & 31;
        const float* w = isg ? wg2 : wl2;
        float acc = (isg ? bg2 : bl2)[oo];
        #pragma unroll
        for (int c = 0; c < 64; ++c) acc = fmaf(w[oo*64+c], f1s[b*1024 + c*16+n], acc);
        acc = fmaxf(acc, 0.f);
        if (isg) gts[b*512 + oo*16+n] = acc; else f2l[b*1024 + o*16+n] = acc;
    }
    __syncthreads();
    if (tid < 64) {
        int b = tid >> 5, j = tid & 31;
        float s = 0.f;
        #pragma unroll
        for (int n = 0; n < 16; ++n) s += gts[b*512 + j*16+n];
        s *= (1.f/16.f);
        #pragma unroll
        for (int n = 0; n < 16; ++n) f2l[b*1024 + (32+j)*16+n] = s;
    }
    __syncthreads();

    // ---- layer 3: wave-row, both batches per row (weights loaded once)
    {
        int n16 = lane & 15, cs = lane >> 4;
        float xr0[16], xr1[16];
        #pragma unroll
        for (int i = 0; i < 16; ++i) {
            xr0[i] = f2l[cs*256 + i*16 + n16];
            xr1[i] = f2l[1024 + cs*256 + i*16 + n16];
        }
        int isg = wid_u >= 4;
        #pragma unroll 2
        for (int k = 0; k < 56; ++k) {
            int r = wid_u*56 + k;
            int rr = isg ? r - 224 : r;
            const float* wrow = (isg ? wg3 : wl3) + rr*64 + cs*16;
            float p0 = 0.f, p1 = 0.f;
            #pragma unroll
            for (int q = 0; q < 4; ++q) {
                float4 w = ((const float4*)wrow)[q];
                p0 = fmaf(w.x, xr0[q*4+0], p0); p0 = fmaf(w.y, xr0[q*4+1], p0);
                p0 = fmaf(w.z, xr0[q*4+2], p0); p0 = fmaf(w.w, xr0[q*4+3], p0);
                p1 = fmaf(w.x, xr1[q*4+0], p1); p1 = fmaf(w.y, xr1[q*4+1], p1);
                p1 = fmaf(w.z, xr1[q*4+2], p1); p1 = fmaf(w.w, xr1[q*4+3], p1);
            }
            p0 += __shfl_xor(p0, 16); p0 += __shfl_xor(p0, 32);
            p1 += __shfl_xor(p1, 16); p1 += __shfl_xor(p1, 32);
            float bb = (isg ? bg3 : bl3)[rr];
            p0 = fmaxf(p0 + bb, 0.f); p1 = fmaxf(p1 + bb, 0.f);
            if (!isg) {
                if (cs == 0) { cat3T[n16*226 + rr] = p0; cat3T[3616 + n16*226 + rr] = p1; }
            } else {
                p0 += __shfl_xor(p0, 1); p0 += __shfl_xor(p0, 2);
                p0 += __shfl_xor(p0, 4); p0 += __shfl_xor(p0, 8);
                p1 += __shfl_xor(p1, 1); p1 += __shfl_xor(p1, 2);
                p1 += __shfl_xor(p1, 4); p1 += __shfl_xor(p1, 8);
                if (lane == 0) {
                    g3m[(rr >> 5)*33 + (rr & 31)] = p0 * (1.f/16.f);
                    g3m[231 + (rr >> 5)*33 + (rr & 31)] = p1 * (1.f/16.f);
                }
            }
        }
    }
    __syncthreads();

    // ---- gather x3 local rows into xB; mp4 precompute
    for (int t = tid; t < 9216; t += 512) {
        int b = t / 4608, rem = t - b*4608;
        int c4 = rem / 576, r2 = rem - c4*576;
        int col = r2 >> 2, ci = r2 & 3, c = c4*4 + ci;
        int p3 = pfn3[col]; int pf = p3 >> 4, pn = p3 & 15;
        xB[b*XB_B + c4*XQS + col*4 + ci] = cat3T[b*3616 + pn*226 + pf*32 + c];
    }
    for (int t = tid; t < 896; t += 512) {
        int b = t >= 448, t2 = t - b*448;
        int pf = t2 >> 6, row = t2 & 63;
        const float* w = ((row < 32) ? wl4 + row*64 : wg4 + (row-32)*64) + 32;
        float s = (row < 32) ? bl4[row] : bg4[row-32];
        #pragma unroll
        for (int q = 0; q < 8; ++q) {
            float4 wv = ((const float4*)w)[q];
            s = fmaf(wv.x, g3m[b*231 + pf*33 + q*4+0], s);
            s = fmaf(wv.y, g3m[b*231 + pf*33 + q*4+1], s);
            s = fmaf(wv.z, g3m[b*231 + pf*33 + q*4+2], s);
            s = fmaf(wv.w, g3m[b*231 + pf*33 + q*4+3], s);
        }
        mp4[b*448 + pf*64 + row] = s;
    }
    __syncthreads();

    // ---- layer 4: xB(x3) -> U(x4 local) + xms4
    {
        int pA = pfn3[lane] >> 4;
        int pB = pfn3[64 + lane] >> 4;
        int pC = pfn3[128 + (lane & 15)] >> 4;
        conv32K(W45h, xB, x4s,
                mp4 + pA*64, mp4 + pB*64, mp4 + pC*64,
                mp4 + 448 + pA*64, mp4 + 448 + pB*64, mp4 + 448 + pC*64,
                xms4, lane, wid_u);
    }
    __syncthreads();
    // ---- mp5
    if (tid < 128) {
        int b = tid >= 64, row = tid & 63;
        const float* w = ((row < 32) ? wl5 + row*64 : wg5 + (row-32)*64) + 32;
        float s = (row < 32) ? bl5[row] : bg5[row-32];
        #pragma unroll
        for (int q = 0; q < 8; ++q) {
            float4 wv = ((const float4*)w)[q];
            s = fmaf(wv.x, xms4[b*32 + q*4+0], s);
            s = fmaf(wv.y, xms4[b*32 + q*4+1], s);
            s = fmaf(wv.z, xms4[b*32 + q*4+2], s);
            s = fmaf(wv.w, xms4[b*32 + q*4+3], s);
        }
        mp5[tid] = s;
    }
    __syncthreads();
    // ---- layer 5: U(x4) -> xB(x5 local) + xms5
    conv32K(W45h + 2048, x4s, xB,
            mp5, mp5, mp5, mp5 + 64, mp5 + 64, mp5 + 64,
            xms5, lane, wid_u);
    __syncthreads();

    // ---- stage wg6h + wl6h into U (x4 dead); mpg6 + mp6 precompute
    #pragma unroll
    for (int k = 0; k < 7; ++k) {
        int t = tid + k*512;                 // t < 3584 float4
        int half = t >= 1792, t2 = t - half*1792;
        int row = t2 >> 3, q = t2 & 7;
        const float* src = half ? (wl6 + row*64) : (wg6 + row*64);
        *(float4*)&U[half*7168 + row*32 + q*4] = *(const float4*)&src[q*4];
    }
    for (int t = tid; t < 896; t += 512) {
        int b = t >= 448, t2 = t - b*448;
        int isw = t2 >= 224, row = t2 - isw*224;
        const float* w = (isw ? wl6 + row*64 : wg6 + row*64) + 32;
        float s = isw ? bl6[row] : bg6[row];
        #pragma unroll
        for (int q = 0; q < 8; ++q) {
            float4 wv = ((const float4*)w)[q];
            s = fmaf(wv.x, xms5[b*32 + q*4+0], s);
            s = fmaf(wv.y, xms5[b*32 + q*4+1], s);
            s = fmaf(wv.z, xms5[b*32 + q*4+2], s);
            s = fmaf(wv.w, xms5[b*32 + q*4+3], s);
        }
        if (isw) mp6[b*224 + row] = s; else mpg6[b*224 + row] = s;
    }
    __syncthreads();

    // ---- g6m: waves 0-3 batch0, 4-7 batch1; 56 rows/wave; x cached in regs
    {
        int bb = wid_u >= 4, w4 = wid_u & 3;
        int r0 = w4 * 56;
        int c0 = lane, c1 = 64 + lane, c2 = 128 + (lane & 15);
        const float* xb = xB + bb*XB_B;
        float4 xc0[8], xc1[8], xc2[8];
        #pragma unroll
        for (int q = 0; q < 8; ++q) {
            xc0[q] = *(const float4*)&xb[q*XQS + c0*4];
            xc1[q] = *(const float4*)&xb[q*XQS + c1*4];
            xc2[q] = *(const float4*)&xb[q*XQS + c2*4];
        }
        #pragma unroll 1
        for (int k = 0; k < 56; ++k) {
            int r = r0 + k;
            const float* wr = wg6h + r*32;
            float bb0 = mpg6[bb*224 + r];
            float v0 = bb0, v1 = bb0, v2 = bb0;
            #pragma unroll
            for (int q = 0; q < 8; ++q) {
                float4 w = *(const float4*)&wr[q*4];
                v0 = fmaf(w.x,xc0[q].x,v0); v0 = fmaf(w.y,xc0[q].y,v0); v0 = fmaf(w.z,xc0[q].z,v0); v0 = fmaf(w.w,xc0[q].w,v0);
                v1 = fmaf(w.x,xc1[q].x,v1); v1 = fmaf(w.y,xc1[q].y,v1); v1 = fmaf(w.z,xc1[q].z,v1); v1 = fmaf(w.w,xc1[q].w,v1);
                v2 = fmaf(w.x,xc2[q].x,v2); v2 = fmaf(w.y,xc2[q].y,v2); v2 = fmaf(w.z,xc2[q].z,v2); v2 = fmaf(w.w,xc2[q].w,v2);
            }
            float s = fmaxf(v0,0.f) + fmaxf(v1,0.f) + ((lane < 16) ? fmaxf(v2,0.f) : 0.f);
            #pragma unroll
            for (int off = 1; off < 64; off <<= 1) s += __shfl_xor(s, off);
            if (lane == 0) g6m[bb*224 + r] = s * (1.f/144.f);
        }
    }
    __syncthreads();

    // ---- sgf
    for (int t = tid; t < 896; t += 512) {
        int b = t >= 448, t2 = t - b*448;
        int f = t2 >> 6, o7 = t2 & 63;
        const float* w = ((o7 < 32) ? wl7 + o7*64 : wg7 + (o7-32)*64) + 32;
        float s = (o7 < 32) ? bl7[o7] : bg7[o7-32];
        #pragma unroll
        for (int q = 0; q < 8; ++q) {
            float4 wv = ((const float4*)w)[q];
            s = fmaf(wv.x, g6m[b*224 + f*32 + q*4+0], s);
            s = fmaf(wv.y, g6m[b*224 + f*32 + q*4+1], s);
            s = fmaf(wv.z, g6m[b*224 + f*32 + q*4+2], s);
            s = fmaf(wv.w, g6m[b*224 + f*32 + q*4+3], s);
        }
        sgf[b*448 + f*64 + o7] = s;
    }
    __syncthreads();

    // ---- main: 63 tasks (f, colgroup), 8 lanes/task, 2 cols/lane, 2 batches
    float gacc0 = 0.f, gacc1 = 0.f;
    {
        int t = 8*wid_u + (lane >> 3);
        bool valid = t < 63;
        int tt = valid ? t : 62;
        int f = tt / 9, g = tt - f*9;
        int colA = g*16 + (lane & 7), colB = colA + 8;
        const float* wfh = wl6h + f*1024;

        float a0A[32], a0B[32], a1A[32], a1B[32];
        #pragma unroll
        for (int o = 0; o < 32; ++o) { a0A[o]=0.f; a0B[o]=0.f; a1A[o]=0.f; a1B[o]=0.f; }
        #pragma unroll 1
        for (int kb = 0; kb < 4; ++kb) {
            int ca = kb*2, cb = kb*2 + 1;
            float4 xA0 = *(const float4*)&xB[ca*XQS + colA*4];
            float4 xA1 = *(const float4*)&xB[cb*XQS + colA*4];
            float4 xB0 = *(const float4*)&xB[ca*XQS + colB*4];
            float4 xB1 = *(const float4*)&xB[cb*XQS + colB*4];
            float4 yA0 = *(const float4*)&xB[XB_B + ca*XQS + colA*4];
            float4 yA1 = *(const float4*)&xB[XB_B + cb*XQS + colA*4];
            float4 yB0 = *(const float4*)&xB[XB_B + ca*XQS + colB*4];
            float4 yB1 = *(const float4*)&xB[XB_B + cb*XQS + colB*4];
            const float* wb = wfh + kb*8;
            #pragma unroll
            for (int o = 0; o < 32; ++o) {
                float4 w0 = *(const float4*)&wb[o*32];
                float4 w1 = *(const float4*)&wb[o*32 + 4];
                a0A[o] = fmaf(w0.x,xA0.x,a0A[o]); a0A[o] = fmaf(w0.y,xA0.y,a0A[o]);
                a0A[o] = fmaf(w0.z,xA0.z,a0A[o]); a0A[o] = fmaf(w0.w,xA0.w,a0A[o]);
                a0A[o] = fmaf(w1.x,xA1.x,a0A[o]); a0A[o] = fmaf(w1.y,xA1.y,a0A[o]);
                a0A[o] = fmaf(w1.z,xA1.z,a0A[o]); a0A[o] = fmaf(w1.w,xA1.w,a0A[o]);
                a0B[o] = fmaf(w0.x,xB0.x,a0B[o]); a0B[o] = fmaf(w0.y,xB0.y,a0B[o]);
                a0B[o] = fmaf(w0.z,xB0.z,a0B[o]); a0B[o] = fmaf(w0.w,xB0.w,a0B[o]);
                a0B[o] = fmaf(w1.x,xB1.x,a0B[o]); a0B[o] = fmaf(w1.y,xB1.y,a0B[o]);
                a0B[o] = fmaf(w1.z,xB1.z,a0B[o]); a0B[o] = fmaf(w1.w,xB1.w,a0B[o]);
                a1A[o] = fmaf(w0.x,yA0.x,a1A[o]); a1A[o] = fmaf(w0.y,yA0.y,a1A[o]);
                a1A[o] = fmaf(w0.z,yA0.z,a1A[o]); a1A[o] = fmaf(w0.w,yA0.w,a1A[o]);
                a1A[o] = fmaf(w1.x,yA1.x,a1A[o]); a1A[o] = fmaf(w1.y,yA1.y,a1A[o]);
                a1A[o] = fmaf(w1.z,yA1.z,a1A[o]); a1A[o] = fmaf(w1.w,yA1.w,a1A[o]);
                a1B[o] = fmaf(w0.x,yB0.x,a1B[o]); a1B[o] = fmaf(w0.y,yB0.y,a1B[o]);
                a1B[o] = fmaf(w0.z,yB0.z,a1B[o]); a1B[o] = fmaf(w0.w,yB0.w,a1B[o]);
                a1B[o] = fmaf(w1.x,yB1.x,a1B[o]); a1B[o] = fmaf(w1.y,yB1.y,a1B[o]);
                a1B[o] = fmaf(w1.z,yB1.z,a1B[o]); a1B[o] = fmaf(w1.w,yB1.w,a1B[o]);
            }
        }
        #pragma unroll
        for (int o = 0; o < 32; ++o) {
            float m0 = mp6[f*32 + o], m1 = mp6[224 + f*32 + o];
            a0A[o] = fmaxf(a0A[o] + m0, 0.f);
            a0B[o] = fmaxf(a0B[o] + m0, 0.f);
            a1A[o] = fmaxf(a1A[o] + m1, 0.f);
            a1B[o] = fmaxf(a1B[o] + m1, 0.f);
        }
        const float* sg0 = sgf + f*64;
        const float* sg1 = sgf + 448 + f*64;
        float l80A = 0.f, l80B = 0.f, l81A = 0.f, l81B = 0.f;
        float g0A = 0.f, g0B = 0.f, g1A = 0.f, g1B = 0.f;
        #pragma unroll 1
        for (int o7 = 0; o7 < 32; ++o7) {
            float s0 = sg0[o7], s1 = sg1[o7];
            float sA0 = s0, sB0 = s0, sA1 = s1, sB1 = s1;
            const float* wr = W7s + o7*32;
            #pragma unroll
            for (int q = 0; q < 8; ++q) {
                float4 w = *(const float4*)&wr[q*4];
                sA0 = fmaf(w.x,a0A[q*4+0],sA0); sA0 = fmaf(w.y,a0A[q*4+1],sA0);
                sA0 = fmaf(w.z,a0A[q*4+2],sA0); sA0 = fmaf(w.w,a0A[q*4+3],sA0);
                sB0 = fmaf(w.x,a0B[q*4+0],sB0); sB0 = fmaf(w.y,a0B[q*4+1],sB0);
                sB0 = fmaf(w.z,a0B[q*4+2],sB0); sB0 = fmaf(w.w,a0B[q*4+3],sB0);
                sA1 = fmaf(w.x,a1A[q*4+0],sA1); sA1 = fmaf(w.y,a1A[q*4+1],sA1);
                sA1 = fmaf(w.z,a1A[q*4+2],sA1); sA1 = fmaf(w.w,a1A[q*4+3],sA1);
                sB1 = fmaf(w.x,a1B[q*4+0],sB1); sB1 = fmaf(w.y,a1B[q*4+1],sB1);
                sB1 = fmaf(w.z,a1B[q*4+2],sB1); sB1 = fmaf(w.w,a1B[q*4+3],sB1);
            }
            float wgt = wl8s[o7];
            l80A = fmaf(wgt, fmaxf(sA0,0.f), l80A);
            l80B = fmaf(wgt, fmaxf(sB0,0.f), l80B);
            l81A = fmaf(wgt, fmaxf(sA1,0.f), l81A);
            l81B = fmaf(wgt, fmaxf(sB1,0.f), l81B);
        }
        #pragma unroll 1
        for (int o7 = 0; o7 < 32; ++o7) {
            float s0 = sg0[32+o7], s1 = sg1[32+o7];
            float sA0 = s0, sB0 = s0, sA1 = s1, sB1 = s1;
            const float* wr = W7s + (32+o7)*32;
            #pragma unroll
            for (int q = 0; q < 8; ++q) {
                float4 w = *(const float4*)&wr[q*4];
                sA0 = fmaf(w.x,a0A[q*4+0],sA0); sA0 = fmaf(w.y,a0A[q*4+1],sA0);
                sA0 = fmaf(w.z,a0A[q*4+2],sA0); sA0 = fmaf(w.w,a0A[q*4+3],sA0);
                sB0 = fmaf(w.x,a0B[q*4+0],sB0); sB0 = fmaf(w.y,a0B[q*4+1],sB0);
                sB0 = fmaf(w.z,a0B[q*4+2],sB0); sB0 = fmaf(w.w,a0B[q*4+3],sB0);
                sA1 = fmaf(w.x,a1A[q*4+0],sA1); sA1 = fmaf(w.y,a1A[q*4+1],sA1);
                sA1 = fmaf(w.z,a1A[q*4+2],sA1); sA1 = fmaf(w.w,a1A[q*4+3],sA1);
                sB1 = fmaf(w.x,a1B[q*4+0],sB1); sB1 = fmaf(w.y,a1B[q*4+1],sB1);
                sB1 = fmaf(w.z,a1B[q*4+2],sB1); sB1 = fmaf(w.w,a1B[q*4+3],sB1);
            }
            float wgt = wl8s[32+o7];
            g0A = fmaf(wgt, fmaxf(sA0,0.f), g0A);
            g0B = fmaf(wgt, fmaxf(sB0,0.f), g0B);
            g1A = fmaf(wgt, fmaxf(sA1,0.f), g1A);
            g1B = fmaf(wgt, fmaxf(sB1,0.f), g1B);
        }
        if (valid) {
            l8v[f*144 + colA] = l80A;
            l8v[f*144 + colB] = l80B;
            l8v[1008 + f*144 + colA] = l81A;
            l8v[1008 + f*144 + colB] = l81B;
            gacc0 = fmaf((float)cnt[f*144 + colA], g0A, gacc0);
            gacc0 = fmaf((float)cnt[f*144 + colB], g0B, gacc0);
            gacc1 = fmaf((float)cnt[f*144 + colA], g1A, gacc1);
            gacc1 = fmaf((float)cnt[f*144 + colB], g1B, gacc1);
        }
    }

    // ---- reduce -> Cb per batch
    #pragma unroll
    for (int off = 32; off > 0; off >>= 1) { gacc0 += __shfl_down(gacc0, off); gacc1 += __shfl_down(gacc1, off); }
    if (lane == 0) { redbuf[wid] = gacc0; redbuf[8 + wid] = gacc1; }
    __syncthreads();
    if (tid < 2) {
        float s = 0.f;
        #pragma unroll
        for (int i = 0; i < 8; ++i) s += redbuf[tid*8 + i];
        CbS[tid] = bl8[0] + s * (1.f/1296.f);
    }
    __syncthreads();
    for (int t = tid; t < 2592; t += 512) {
        int b = t >= 1296, idx = t - b*1296;
        out[(2*blk + b)*1296 + idx] = PI_F * (l8v[b*1008 + pml[idx]] + CbS[b]);
    }
}

extern "C" void kernel_launch(void* const* d_in, const int* in_sizes, int n_in,
                              void* d_out, int out_size, void* d_ws, size_t ws_size,
                              hipStream_t stream) {
    (void)in_sizes; (void)n_in; (void)out_size; (void)d_ws; (void)ws_size;
    const float* ch  = (const float*)d_in[0];
    const float* wl1 = (const float*)d_in[1];  const float* bl1v = (const float*)d_in[2];
    const float* wg1 = (const float*)d_in[3];  const float* bg1v = (const float*)d_in[4];
    const float* wl2 = (const float*)d_in[5];  const float* bl2v = (const float*)d_in[6];
    const float* wg2 = (const float*)d_in[7];  const float* bg2v = (const float*)d_in[8];
    const float* wl4 = (const float*)d_in[9];  const float* bl4v = (const float*)d_in[10];
    const float* wg4 = (const float*)d_in[11]; const float* bg4v = (const float*)d_in[12];
    const float* wl5 = (const float*)d_in[13]; const float* bl5v = (const float*)d_in[14];
    const float* wg5 = (const float*)d_in[15]; const float* bg5v = (const float*)d_in[16];
    const float* wl7 = (const float*)d_in[17]; const float* bl7v = (const float*)d_in[18];
    const float* wg7 = (const float*)d_in[19]; const float* bg7v = (const float*)d_in[20];
    const float* wl3 = (const float*)d_in[21]; const float* bl3v = (const float*)d_in[22];
    const float* wg3 = (const float*)d_in[23]; const float* bg3v = (const float*)d_in[24];
    const float* wl6 = (const float*)d_in[25]; const float* bl6v = (const float*)d_in[26];
    const float* wg6 = (const float*)d_in[27]; const float* bg6v = (const float*)d_in[28];
    const float* wl8 = (const float*)d_in[29]; const float* bl8v = (const float*)d_in[30];
    const int* perm3 = (const int*)d_in[31];
    const int* perm6 = (const int*)d_in[32];
    float* out = (float*)d_out;

    kfull<<<256, 512, 0, stream>>>(ch,
        wl1, bl1v, wg1, bg1v, wl2, bl2v, wg2, bg2v,
        wl3, bl3v, wg3, bg3v, wl4, bl4v, wg4, bg4v,
        wl5, bl5v, wg5, bg5v, wl6, bl6v, wg6, bg6v,
        wl7, bl7v, wg7, bg7v, wl8, bl8v, perm3, perm6, out);
}